// Round 6
// baseline (1483.242 us; speedup 1.0000x reference)
//
#include <hip/hip_runtime.h>
#include <math.h>

typedef __bf16 bf16_t;
typedef bf16_t bf16x8 __attribute__((ext_vector_type(8)));
typedef bf16_t bf16x4 __attribute__((ext_vector_type(4)));
typedef bf16_t bf16x2 __attribute__((ext_vector_type(2)));
typedef float  f32x4  __attribute__((ext_vector_type(4)));

#define N_NODES 20000
#define NEDGE   320000
#define DIM     128
#define TP      136           // LDS band row stride (elems)
#define EBLK    2500          // NEDGE / 128 (fused edge blocks, 4 waves x 32 edges)
#define FBLK    10000         // NEDGE / 32  (per-wave partial count)
#define NBLK    625           // N_NODES / 32
#define GPRE    157           // ceil(20000 / 128) PRE tail blocks
#define PBLK    512           // pooled-edge blocks (16 waves each)

// ---- WF (MFMA b-frag-layout weights, bf16); each 128x128 chunk = 16384 elems = 32KB ----
// chunk layout: [kk 0..3][ct 0..7][lane 0..63][j 0..7]
#define FE1  0
#define FE2  49152
#define FM1  65536
#define FM2  98304
#define FU1  114688
#define FU2  163840
#define FK   180224
#define FV   196608
#define WF_ELEMS 212992

// ---------------- shared helpers ----------------
__device__ __forceinline__ void acc_zero32(f32x4 acc[2][8]) {
  f32x4 z = {0.f, 0.f, 0.f, 0.f};
#pragma unroll
  for (int i = 0; i < 2; ++i)
#pragma unroll
    for (int j = 0; j < 8; ++j) acc[i][j] = z;
}

// ---- 32-row band staging (2 lanes per row, 8x16B per lane) ----
__device__ __forceinline__ void wstage_rows_bf(bf16_t* sA, const bf16_t* src, int rowreg, int lane) {
  int r = lane >> 1, h = lane & 1;
  int row = __shfl(rowreg, r);
  const bf16_t* sp = src + (size_t)row * DIM + h * 64;
  bf16_t* dp = sA + r * TP + h * 64;
#pragma unroll
  for (int i = 0; i < 8; ++i)
    *(uint4*)(dp + i * 8) = *(const uint4*)(sp + i * 8);
}

__device__ __forceinline__ void wstage_rows_f32(bf16_t* sA, const float* src, int rowreg, int lane) {
  int r = lane >> 1, h = lane & 1;
  int row = __shfl(rowreg, r);
  const float* sp = src + (size_t)row * DIM + h * 64;
  bf16_t* dp = sA + r * TP + h * 64;
#pragma unroll
  for (int i = 0; i < 8; ++i) {
    float4 f0 = *(const float4*)(sp + i * 8);
    float4 f1 = *(const float4*)(sp + i * 8 + 4);
    bf16x8 tv;
    tv[0]=(bf16_t)f0.x; tv[1]=(bf16_t)f0.y; tv[2]=(bf16_t)f0.z; tv[3]=(bf16_t)f0.w;
    tv[4]=(bf16_t)f1.x; tv[5]=(bf16_t)f1.y; tv[6]=(bf16_t)f1.z; tv[7]=(bf16_t)f1.w;
    *(bf16x8*)(dp + i * 8) = tv;
  }
}

__device__ __forceinline__ void wstage_seq_bf(bf16_t* sA, const bf16_t* src, int base, int lane) {
  int r = lane >> 1, h = lane & 1;
  const bf16_t* sp = src + (size_t)(base + r) * DIM + h * 64;
  bf16_t* dp = sA + r * TP + h * 64;
#pragma unroll
  for (int i = 0; i < 8; ++i)
    *(uint4*)(dp + i * 8) = *(const uint4*)(sp + i * 8);
}

__device__ __forceinline__ void wstage_seq_f32(bf16_t* sA, const float* src, int base, int lane) {
  int r = lane >> 1, h = lane & 1;
  const float* sp = src + (size_t)(base + r) * DIM + h * 64;
  bf16_t* dp = sA + r * TP + h * 64;
#pragma unroll
  for (int i = 0; i < 8; ++i) {
    float4 f0 = *(const float4*)(sp + i * 8);
    float4 f1 = *(const float4*)(sp + i * 8 + 4);
    bf16x8 tv;
    tv[0]=(bf16_t)f0.x; tv[1]=(bf16_t)f0.y; tv[2]=(bf16_t)f0.z; tv[3]=(bf16_t)f0.w;
    tv[4]=(bf16_t)f1.x; tv[5]=(bf16_t)f1.y; tv[6]=(bf16_t)f1.z; tv[7]=(bf16_t)f1.w;
    *(bf16x8*)(dp + i * 8) = tv;
  }
}

// stage a full 32KB weight chunk into LDS cooperatively (256 threads x 128B) - PRE path only
__device__ __forceinline__ void chunk_stage(bf16_t* ch, const bf16_t* __restrict__ src, int t) {
#pragma unroll
  for (int i = 0; i < 8; ++i) {
    int idx = (i * 256 + t) * 8;
    *(uint4*)(ch + idx) = *(const uint4*)(src + idx);
  }
}

// one K=128 MFMA pass: A from private band, B-frags from LDS chunk
__device__ __forceinline__ void wmfma_lds(const bf16_t* sA, const bf16_t* ch,
                                          int lane, int lm, int lq, f32x4 acc[2][8]) {
#pragma unroll
  for (int kk = 0; kk < 4; ++kk) {
    int ko = kk * 32 + lq * 8;
    bf16x8 a0 = *(const bf16x8*)(sA + lm * TP + ko);
    bf16x8 a1 = *(const bf16x8*)(sA + (16 + lm) * TP + ko);
    const bf16_t* wp = ch + (kk << 12) + (lane << 3);
#pragma unroll
    for (int ct = 0; ct < 8; ++ct) {
      bf16x8 bfr = *(const bf16x8*)(wp + (ct << 9));
      acc[0][ct] = __builtin_amdgcn_mfma_f32_16x16x32_bf16(a0, bfr, acc[0][ct], 0, 0, 0);
      acc[1][ct] = __builtin_amdgcn_mfma_f32_16x16x32_bf16(a1, bfr, acc[1][ct], 0, 0, 0);
    }
  }
}

// one K=128 MFMA pass with B-frags streamed from global WF (small kernels)
__device__ __forceinline__ void wmfma_gk128(const bf16_t* sA, const bf16_t* __restrict__ Wf,
                                            int lane, int lm, int lq, f32x4 acc[2][8]) {
#pragma unroll
  for (int kk = 0; kk < 4; ++kk) {
    int ko = kk * 32 + lq * 8;
    bf16x8 a0 = *(const bf16x8*)(sA + lm * TP + ko);
    bf16x8 a1 = *(const bf16x8*)(sA + (16 + lm) * TP + ko);
    const bf16_t* wp = Wf + ((kk * 8) << 9) + (lane << 3);
#pragma unroll
    for (int ct = 0; ct < 8; ++ct) {
      bf16x8 bfr = *(const bf16x8*)(wp + (ct << 9));
      acc[0][ct] = __builtin_amdgcn_mfma_f32_16x16x32_bf16(a0, bfr, acc[0][ct], 0, 0, 0);
      acc[1][ct] = __builtin_amdgcn_mfma_f32_16x16x32_bf16(a1, bfr, acc[1][ct], 0, 0, 0);
    }
  }
}

// online-softmax merge over 2^k lanes, state (m,s)
__device__ __forceinline__ void merge_shfl(float& m, float& s, int width) {
  for (int k = 1; k < width; k <<= 1) {
    float m2 = __shfl_xor(m, k), s2 = __shfl_xor(s, k);
    float M = fmaxf(m, m2), ns = 0.f;
    if (m  > -1e29f) ns += s  * expf(m  - M);
    if (m2 > -1e29f) ns += s2 * expf(m2 - M);
    m = M; s = ns;
  }
}

// ---------------- prep kernels ----------------
__global__ void gn_xcvt(const float* x, bf16_t* xb) {
  int i = blockIdx.x * 256 + threadIdx.x;
  if (i < N_NODES * DIM / 4) {
    float4 f = ((const float4*)x)[i];
    bf16x4 o; o[0]=(bf16_t)f.x; o[1]=(bf16_t)f.y; o[2]=(bf16_t)f.z; o[3]=(bf16_t)f.w;
    *(bf16x4*)(xb + (size_t)i * 4) = o;
  }
}

__global__ void gn_fragw(const float* We1, const float* We2, const float* Wm1, const float* Wm2,
                         const float* Wu1, const float* Wu2, const float* Wk, const float* Wv,
                         bf16_t* WF) {
  int idx = blockIdx.x * 256 + threadIdx.x;
  if (idx >= WF_ELEMS) return;
  int seg = idx >> 14;
  const float* W; int kc;
  switch (seg) {
    case 0:  W = We1; kc = 0; break;
    case 1:  W = We1; kc = 1; break;
    case 2:  W = We1; kc = 2; break;
    case 3:  W = We2; kc = 0; break;
    case 4:  W = Wm1; kc = 0; break;
    case 5:  W = Wm1; kc = 1; break;
    case 6:  W = Wm2; kc = 0; break;
    case 7:  W = Wu1; kc = 0; break;
    case 8:  W = Wu1; kc = 1; break;
    case 9:  W = Wu1; kc = 2; break;
    case 10: W = Wu2; kc = 0; break;
    case 11: W = Wk;  kc = 0; break;
    default: W = Wv;  kc = 0; break;
  }
  int r = idx & 16383;
  int j = r & 7, lane = (r >> 3) & 63, ct = (r >> 9) & 7, kk = (r >> 12) & 3;
  int k = kc * 128 + kk * 32 + (lane >> 4) * 8 + j;
  int n = ct * 16 + (lane & 15);
  WF[idx] = (bf16_t)W[k * 128 + n];
}

// Rp = (u @ W_e1[384:512] + b_e1) in epilogue-transposed layout Rp[g*128 + lm*8 + ct]
// uw = u @ W_w[128:256] + b_w
__global__ void gn_uprep(const float* u, const float* We1, const float* be1,
                         const float* Ww, const float* bw, float* Rp, float* uw) {
  int t = threadIdx.x;
  for (int idx = blockIdx.x * 256 + t; idx < 32 * 128; idx += gridDim.x * 256) {
    int g = idx >> 7, c = idx & 127;
    float acc = be1[c];
    for (int k = 0; k < 128; ++k) acc += u[g * 128 + k] * We1[(384 + k) * 128 + c];
    Rp[g * 128 + (c & 15) * 8 + (c >> 4)] = acc;
  }
  if (blockIdx.x == 0 && t < 32) {
    float acc = bw[0];
    for (int k = 0; k < 128; ++k) acc += u[t * 128 + k] * Ww[128 + k];
    uw[t] = acc;
  }
}

// int in-degree count
__global__ void gn_counti(const int* ei, int* cnti) {
  int e = blockIdx.x * 256 + threadIdx.x;
  if (e < NEDGE) atomicAdd(&cnti[ei[NEDGE + e]], 1);
}

// single-block exclusive scan of cnti -> off (and cursor copy)
__global__ void gn_scan(const int* cnti, int* off, int* curs) {
  __shared__ int part[256];
  int t = threadIdx.x;
  int base = t * 80;
  int lim = base + 80; if (lim > N_NODES) lim = N_NODES;
  int s = 0;
  for (int i = base; i < lim; ++i) s += cnti[i];
  part[t] = s;
  __syncthreads();
  for (int d = 1; d < 256; d <<= 1) {
    int add = (t >= d) ? part[t - d] : 0;
    __syncthreads();
    part[t] += add;
    __syncthreads();
  }
  int pfx = (t == 0) ? 0 : part[t - 1];
  for (int i = base; i < lim; ++i) {
    off[i] = pfx; curs[i] = pfx; pfx += cnti[i];
  }
  if (t == 0) off[N_NODES] = NEDGE;
}

// scatter edge ids into CSR order by destination
__global__ void gn_eidx(const int* ei, int* curs, int* eidx) {
  int e = blockIdx.x * 256 + threadIdx.x;
  if (e < NEDGE) {
    int c = ei[NEDGE + e];
    int pos = atomicAdd(&curs[c], 1);
    eidx[pos] = e;
  }
}

__global__ void gn_q(const float* qa, const float* Wq, const float* bq, float* qb) {
  int b = blockIdx.x, t = threadIdx.x;
  int c = t & 127, half = t >> 7;
  const float* qrow = qa + b * 1024 + half * 512;
  float acc = 0.f;
  for (int k = 0; k < 512; ++k) acc += qrow[k] * Wq[(half * 512 + k) * 128 + c];
  __shared__ float red[256];
  red[t] = acc;
  __syncthreads();
  if (half == 0) qb[b * 128 + c] = red[c] + red[128 + c] + bq[c];
}

__global__ void gn_wl0(const float* ea, const float* Ww, const float* uw,
                       const int* ei, const int* nbat, float* wl, int* gb) {
  int t = threadIdx.x;
  int sub = t & 15, grp = t >> 4;
  for (int e = blockIdx.x * 16 + grp; e < NEDGE; e += gridDim.x * 16) {
    const float* er = ea + (size_t)e * DIM + sub * 8;
    float s = 0.f;
#pragma unroll
    for (int j = 0; j < 8; ++j) s += er[j] * Ww[sub * 8 + j];
#pragma unroll
    for (int m = 1; m < 16; m <<= 1) s += __shfl_xor(s, m);
    if (sub == 0) {
      int g = nbat[ei[e]];
      wl[e] = s + uw[g];
      gb[e] = g;
    }
  }
}

__global__ void gn_part0(const float* wl, const int* gb, float* pm, float* ps) {
  __shared__ float lv[128];
  __shared__ int   lgg[128];
  int t = threadIdx.x, blk = blockIdx.x, e0 = blk * 128;
  if (t < 128) { lv[t] = wl[e0 + t]; lgg[t] = gb[e0 + t]; }
  __syncthreads();
  int g = t >> 3, seg = t & 7;
  float m = -1e30f, s = 0.f;
  for (int i = seg * 16; i < seg * 16 + 16; ++i)
    if (lgg[i] == g) {
      float v = lv[i];
      if (v > m) { s = s * expf(m - v) + 1.f; m = v; }
      else s += expf(v - m);
    }
  merge_shfl(m, s, 8);
  if (seg == 0) { pm[blk * 32 + g] = m; ps[blk * 32 + g] = s; }
}

__global__ void gn_reduce_ms(const float* pm, const float* ps, float* mg, float* sg, int nb) {
  int g = blockIdx.x, t = threadIdx.x;
  __shared__ float red[256];
  float m = -1e30f;
  for (int i = t; i < nb; i += 256) m = fmaxf(m, pm[i * 32 + g]);
  red[t] = m; __syncthreads();
  for (int s2 = 128; s2 > 0; s2 >>= 1) { if (t < s2) red[t] = fmaxf(red[t], red[t + s2]); __syncthreads(); }
  m = red[0]; __syncthreads();
  float s = 0.f;
  for (int i = t; i < nb; i += 256) {
    float sb = ps[i * 32 + g];
    if (sb > 0.f) s += sb * expf(pm[i * 32 + g] - m);
  }
  red[t] = s; __syncthreads();
  for (int s2 = 128; s2 > 0; s2 >>= 1) { if (t < s2) red[t] += red[t + s2]; __syncthreads(); }
  if (t == 0) { mg[g] = m; sg[g] = red[0]; }
}

// ---------------- fused edge+message kernel ----------------
// 4 waves/block, private 32-edge bands. The 32KB weight chunk for pass p+1 is
// prefetched into REGISTERS during pass p's MFMA (T14 async-STAGE split), then
// ds_written between barriers. Barrier cost drops from L2-latency to LDS-write.
__global__ __launch_bounds__(256, 2) void gn_fused(
    const bf16_t* __restrict__ xb,
    const void* esrcv, int efirst,
    bf16_t* edst,
    const bf16_t* __restrict__ WF,
    const float* Rp, const float* UW, const float* Wwv,
    const float* be2, const float* bm1, const float* bm2,
    const float* wl_cur, const float* mg, const float* sg,
    float* wl_next, float* pm, float* ps, int last,
    const int* ei, const int* gb, bf16_t* msg,
    const float* uu, const float* bu1, const int* nbat, float* pre,
    float* nwout) {
  __shared__ bf16_t chunk[16384];
  __shared__ bf16_t band[4][32 * TP];
  __shared__ float slwt[128];

  int t = threadIdx.x;
  int w = t >> 6, lane = t & 63;
  int lm = lane & 15, lq = lane >> 4;
  int blk = blockIdx.x;
  bf16_t* myband = band[w];

  if (blk >= EBLK) {
    // ---- PRE node partial: 128 nodes per block, 32 per wave ----
    int nb128 = blk - EBLK;
    int gb32 = nb128 * 4 + w;
    int lrow = 0, lgr = 0;
    if (lane < 32) {
      int node = gb32 * 32 + lane;
      if (node > N_NODES - 1) node = N_NODES - 1;
      lrow = node;
      lgr = nbat[node];
    }
    f32x4 acc[2][8];
    acc_zero32(acc);
    wstage_rows_bf(myband, xb, lrow, lane);
    chunk_stage(chunk, WF + FU1, t);
    __syncthreads();
    wmfma_lds(myband, chunk, lane, lm, lq, acc);             // x part
    __syncthreads();
    wstage_rows_f32(myband, uu, lgr, lane);
    chunk_stage(chunk, WF + FU1 + 32768, t);
    __syncthreads();
    wmfma_lds(myband, chunk, lane, lm, lq, acc);             // u part
    if (gb32 < NBLK) {
      // coalesced layout: pre[gb32*4096 + idx*64 + lane]
      float* pp = pre + (size_t)gb32 * 4096 + lane;
#pragma unroll
      for (int rt = 0; rt < 2; ++rt)
#pragma unroll
        for (int reg = 0; reg < 4; ++reg)
#pragma unroll
          for (int ct = 0; ct < 8; ++ct)
            pp[((rt * 32 + reg * 8 + ct) << 6)] = acc[rt][ct][reg] + bu1[ct * 16 + lm];
    }
    return;
  }

  int e0 = blk * 128;
  int ew0 = e0 + w * 32;               // this wave's first edge
  int lrowr = 0, lcolr = 0, lgr = 0;
  float lnwr = 0.f;
  if (lane < 32) {
    int e = ew0 + lane;
    lrowr = ei[e];
    lcolr = ei[NEDGE + e];
    lgr = gb[e];
    lnwr = expf(wl_cur[e] - mg[lgr]) / sg[lgr];
    if (last) nwout[e] = lnwr;         // feed the pooled-edge kernel (no expf there)
  }

  f32x4 accE[2][8], accM[2][8];
  acc_zero32(accE);
  acc_zero32(accM);

  uint4 c0, c1, c2, c3, c4, c5, c6, c7;
#define CLOAD(SRC) { const uint4* _s = (const uint4*)(SRC) + t; \
  c0 = _s[0];    c1 = _s[256];  c2 = _s[512];  c3 = _s[768]; \
  c4 = _s[1024]; c5 = _s[1280]; c6 = _s[1536]; c7 = _s[1792]; }
#define CWRITE() { uint4* _d = (uint4*)chunk + t; \
  _d[0] = c0;    _d[256] = c1;  _d[512] = c2;  _d[768] = c3; \
  _d[1024] = c4; _d[1280] = c5; _d[1536] = c6; _d[1792] = c7; }

  // prologue: chunk C0 = E1c0; band B0 = x[row]
  CLOAD(WF + FE1);
  wstage_rows_bf(myband, xb, lrowr, lane);
  CWRITE();
  __syncthreads();

  // pass 0: E1c0; prefetch FM1c0
  CLOAD(WF + FM1);
  wmfma_lds(myband, chunk, lane, lm, lq, accE);
  __syncthreads();
  CWRITE();
  __syncthreads();

  // pass 1: M1c0 (same band); prefetch E1c1; restage band = x[col]
  CLOAD(WF + FE1 + 16384);
  wmfma_lds(myband, chunk, lane, lm, lq, accM);
  wstage_rows_bf(myband, xb, lcolr, lane);
  __syncthreads();
  CWRITE();
  __syncthreads();

  // pass 2: E1c1; prefetch E1c2; restage band = old edge_attr
  CLOAD(WF + FE1 + 32768);
  wmfma_lds(myband, chunk, lane, lm, lq, accE);
  if (efirst) wstage_seq_f32(myband, (const float*)esrcv, ew0, lane);
  else        wstage_seq_bf (myband, (const bf16_t*)esrcv, ew0, lane);
  __syncthreads();
  CWRITE();
  __syncthreads();

  // pass 3: E1c2; prefetch E2; epi1 hidden_e = relu(accE + Rp[g]) -> band
  CLOAD(WF + FE2);
  wmfma_lds(myband, chunk, lane, lm, lq, accE);
#pragma unroll
  for (int rt = 0; rt < 2; ++rt)
#pragma unroll
    for (int reg = 0; reg < 4; ++reg) {
      int row = rt * 16 + lq * 4 + reg;
      int g = __shfl(lgr, row);
      const float4* rp = (const float4*)(Rp + (size_t)g * 128 + lm * 8);
      float4 ra = rp[0], rb = rp[1];
      float rv[8] = {ra.x, ra.y, ra.z, ra.w, rb.x, rb.y, rb.z, rb.w};
#pragma unroll
      for (int ct = 0; ct < 8; ++ct) {
        int col = ct * 16 + lm;
        myband[row * TP + col] = (bf16_t)fmaxf(accE[rt][ct][reg] + rv[ct], 0.f);
      }
    }
  acc_zero32(accE);
  __syncthreads();
  CWRITE();
  __syncthreads();

  // pass 4: E2; prefetch M1c1; epi2 new_edge -> band + EB (vectorized) + logits
  CLOAD(WF + FM1 + 16384);
  wmfma_lds(myband, chunk, lane, lm, lq, accE);
  {
    float ww8[8], be8[8];
#pragma unroll
    for (int ct = 0; ct < 8; ++ct) { ww8[ct] = Wwv[ct * 16 + lm]; be8[ct] = be2[ct * 16 + lm]; }
#pragma unroll
    for (int rt = 0; rt < 2; ++rt)
#pragma unroll
      for (int reg = 0; reg < 4; ++reg) {
        int row = rt * 16 + lq * 4 + reg;
        int g = __shfl(lgr, row);
        float lsum = 0.f;
#pragma unroll
        for (int ct = 0; ct < 8; ++ct) {
          int col = ct * 16 + lm;
          float v = accE[rt][ct][reg] + be8[ct];
          myband[row * TP + col] = (bf16_t)v;
          lsum += v * ww8[ct];
        }
        if (!last) {
          lsum += __shfl_xor(lsum, 1);
          lsum += __shfl_xor(lsum, 2);
          lsum += __shfl_xor(lsum, 4);
          lsum += __shfl_xor(lsum, 8);
          if (lm == 0) {
            float v2 = lsum + UW[g];
            wl_next[ew0 + row] = v2;
            slwt[w * 32 + row] = v2;
          }
        }
      }
    // vectorized EB store from band (8 x uint4 per lane-pair)
    int r = lane >> 1, h = lane & 1;
    bf16_t* dp = edst + (size_t)(ew0 + r) * DIM + h * 64;
    const bf16_t* sp2 = myband + r * TP + h * 64;
#pragma unroll
    for (int i = 0; i < 8; ++i)
      *(uint4*)(dp + i * 8) = *(const uint4*)(sp2 + i * 8);
  }
  __syncthreads();
  CWRITE();
  __syncthreads();

  // pass 5: M1c1; prefetch M2; epi3 hidden_m = relu(accM + bm1) -> band
  CLOAD(WF + FM2);
  wmfma_lds(myband, chunk, lane, lm, lq, accM);
  {
    float bm18[8];
#pragma unroll
    for (int ct = 0; ct < 8; ++ct) bm18[ct] = bm1[ct * 16 + lm];
#pragma unroll
    for (int rt = 0; rt < 2; ++rt)
#pragma unroll
      for (int reg = 0; reg < 4; ++reg) {
        int row = rt * 16 + lq * 4 + reg;
#pragma unroll
        for (int ct = 0; ct < 8; ++ct) {
          int col = ct * 16 + lm;
          myband[row * TP + col] = (bf16_t)fmaxf(accM[rt][ct][reg] + bm18[ct], 0.f);
        }
      }
  }
  acc_zero32(accM);
  __syncthreads();
  CWRITE();
  __syncthreads();

  // pass 6: M2; epi4 msg -> band -> MSG (vectorized, no atomics)
  wmfma_lds(myband, chunk, lane, lm, lq, accM);
  {
    float bm28[8];
#pragma unroll
    for (int ct = 0; ct < 8; ++ct) bm28[ct] = bm2[ct * 16 + lm];
#pragma unroll
    for (int rt = 0; rt < 2; ++rt)
#pragma unroll
      for (int reg = 0; reg < 4; ++reg) {
        int row = rt * 16 + lq * 4 + reg;
        float nwv = __shfl(lnwr, row);
#pragma unroll
        for (int ct = 0; ct < 8; ++ct) {
          int col = ct * 16 + lm;
          myband[row * TP + col] = (bf16_t)((accM[rt][ct][reg] + bm28[ct]) * nwv);
        }
      }
    int r = lane >> 1, h = lane & 1;
    bf16_t* dp = msg + (size_t)(ew0 + r) * DIM + h * 64;
    const bf16_t* sp2 = myband + r * TP + h * 64;
#pragma unroll
    for (int i = 0; i < 8; ++i)
      *(uint4*)(dp + i * 8) = *(const uint4*)(sp2 + i * 8);
  }

  // per-wave softmax partials for next layer
  if (!last) {
    int g = lane >> 1, seg = lane & 1;
    float m = -1e30f, s = 0.f;
    for (int i = seg * 16; i < seg * 16 + 16; ++i) {
      int gi = __shfl(lgr, i);
      if (gi == g) {
        float v = slwt[w * 32 + i];
        if (v > m) { s = s * expf(m - v) + 1.f; m = v; }
        else s += expf(v - m);
      }
    }
    merge_shfl(m, s, 2);
    if (seg == 0) { pm[(blk * 4 + w) * 32 + g] = m; ps[(blk * 4 + w) * 32 + g] = s; }
  }
#undef CLOAD
#undef CWRITE
}

// ---------------- CSR gather: received[n] = (sum msg rows) / max(deg,1) ----------------
__global__ __launch_bounds__(256) void gn_gather(
    const bf16_t* __restrict__ msg, const int* __restrict__ off,
    const int* __restrict__ eidx, bf16_t* recvb) {
  int w = threadIdx.x >> 6, lane = threadIdx.x & 63;
  int n = blockIdx.x * 4 + w;
  int o0 = off[n], o1 = off[n + 1];
  float a0 = 0.f, a1 = 0.f;
  int i = o0;
  int e = (i < o1) ? eidx[i] : 0;
  for (; i < o1; ++i) {
    int en = (i + 1 < o1) ? eidx[i + 1] : 0;
    bf16x2 v = *(const bf16x2*)(msg + (size_t)e * DIM + lane * 2);
    a0 += (float)v[0];
    a1 += (float)v[1];
    e = en;
  }
  float ic = 1.f / fmaxf((float)(o1 - o0), 1.f);
  bf16x2 o; o[0] = (bf16_t)(a0 * ic); o[1] = (bf16_t)(a1 * ic);
  *(bf16x2*)(recvb + (size_t)n * DIM + lane * 2) = o;
}

// ---------------- node update POST kernel ----------------
__global__ __launch_bounds__(64, 3) void gn_node(
    bf16_t* xdst, const bf16_t* recvb, const float* pre,
    const bf16_t* __restrict__ WF, const float* bu2) {
  __shared__ bf16_t sA[32 * TP];

  int lane = threadIdx.x;
  int nb = blockIdx.x;
  int n0 = nb * 32;
  int lm = lane & 15, lq = lane >> 4;

  wstage_seq_bf(sA, recvb, n0, lane);

  f32x4 acc[2][8];
  acc_zero32(acc);
  wmfma_gk128(sA, WF + FU1 + 16384, lane, lm, lq, acc);      // received part

  // hidden_u = relu(acc + PRE)  (coalesced layout: pre[nb*4096 + idx*64 + lane])
  const float* pp = pre + (size_t)nb * 4096 + lane;
#pragma unroll
  for (int rt = 0; rt < 2; ++rt)
#pragma unroll
    for (int reg = 0; reg < 4; ++reg) {
      int row = rt * 16 + lq * 4 + reg;
#pragma unroll
      for (int ct = 0; ct < 8; ++ct) {
        int col = ct * 16 + lm;
        sA[row * TP + col] = (bf16_t)fmaxf(acc[rt][ct][reg] + pp[((rt * 32 + reg * 8 + ct) << 6)], 0.f);
      }
    }
  acc_zero32(acc);
  wmfma_gk128(sA, WF + FU2, lane, lm, lq, acc);

  {
    float bu28[8];
#pragma unroll
    for (int ct = 0; ct < 8; ++ct) bu28[ct] = bu2[ct * 16 + lm];
#pragma unroll
    for (int rt = 0; rt < 2; ++rt)
#pragma unroll
      for (int reg = 0; reg < 4; ++reg) {
        int row = rt * 16 + lq * 4 + reg;
        bf16_t* dr = xdst + (size_t)(n0 + row) * DIM;
#pragma unroll
        for (int ct = 0; ct < 8; ++ct) {
          int col = ct * 16 + lm;
          dr[col] = (bf16_t)(acc[rt][ct][reg] + bu28[ct]);
        }
      }
  }
}

// ---------------- evidence -> K/V projection ----------------
__global__ __launch_bounds__(64, 3) void gn_ev(
    const bf16_t* xsrc, const bf16_t* __restrict__ WF,
    const float* bk, const float* bv, float* kb, float* vb) {
  __shared__ bf16_t sA[32 * TP];

  int lane = threadIdx.x;
  int n0 = blockIdx.x * 32;
  int sel = blockIdx.y;
  const bf16_t* Wf = WF + (sel ? FV : FK);
  const float* bias = sel ? bv : bk;
  float* dst = sel ? vb : kb;
  int lm = lane & 15, lq = lane >> 4;

  {
    int r = lane >> 1, h = lane & 1;
    const bf16_t* sp = xsrc + (size_t)(n0 + r) * DIM + h * 64;
    bf16_t* dp = sA + r * TP + h * 64;
#pragma unroll
    for (int i = 0; i < 8; ++i) {
      uint4 v = *(const uint4*)(sp + i * 8);
      bf16_t tmp[8];
      *(uint4*)tmp = v;
      bf16x8 tv;
#pragma unroll
      for (int j = 0; j < 8; ++j) {
        float f = (float)tmp[j];
        tv[j] = (bf16_t)(0.5f * f * (1.f + erff(f * 0.70710678118654752f)));
      }
      *(bf16x8*)(dp + i * 8) = tv;
    }
  }

  f32x4 acc[2][8];
  acc_zero32(acc);
  wmfma_gk128(sA, Wf, lane, lm, lq, acc);

  {
    float b8[8];
#pragma unroll
    for (int ct = 0; ct < 8; ++ct) b8[ct] = bias[ct * 16 + lm];
#pragma unroll
    for (int rt = 0; rt < 2; ++rt)
#pragma unroll
      for (int reg = 0; reg < 4; ++reg) {
        int row = rt * 16 + lq * 4 + reg;
        float* dr = dst + (size_t)(n0 + row) * DIM;
#pragma unroll
        for (int ct = 0; ct < 8; ++ct) {
          int col = ct * 16 + lm;
          dr[col] = acc[rt][ct][reg] + b8[ct];
        }
      }
  }
}

// ---------------- pooled edge: 16 waves/block, NW precomputed, per-block partials ----------------
__global__ __launch_bounds__(1024, 1) void gn_pooled_edge(
    const bf16_t* __restrict__ eb, const float* __restrict__ nw,
    const int* __restrict__ gb, float* pep) {
  __shared__ float loc[4096];
  int t = threadIdx.x;
  for (int i = t; i < 4096; i += 1024) loc[i] = 0.f;
  __syncthreads();
  int lane = t & 63, w = t >> 6;
  int wid = blockIdx.x * 16 + w;                 // PBLK*16 = 8192 waves
  for (int e = wid; e < NEDGE; e += PBLK * 16) {
    int g = gb[e];
    float nwt = nw[e];
    bf16x2 v = *(const bf16x2*)(eb + (size_t)e * DIM + lane * 2);
    atomicAdd(&loc[g * 128 + lane * 2],     (float)v[0] * nwt);
    atomicAdd(&loc[g * 128 + lane * 2 + 1], (float)v[1] * nwt);
  }
  __syncthreads();
  float* pp = pep + (size_t)blockIdx.x * 4096;
  for (int i = t; i < 4096; i += 1024) pp[i] = loc[i];
}

// ---------------- attention pool ----------------
__global__ void gn_att(const float* qb, const float* kb, const float* vb, const int* non, float* out) {
  int b = blockIdx.x >> 1, h = blockIdx.x & 1, t = threadIdx.x;
  __shared__ float qv[64];
  __shared__ float sc[625];
  __shared__ float red[256];
  if (t < 64) qv[t] = qb[b * 128 + h * 64 + t];
  __syncthreads();
  int nn = non[b];
  const float4* qv4 = (const float4*)qv;
  for (int l = t; l < 625; l += 256) {
    float acc = 0.f;
    const float4* kr = (const float4*)(kb + ((size_t)(b * 625 + l)) * DIM + h * 64);
#pragma unroll
    for (int d2 = 0; d2 < 16; ++d2) {
      float4 kv = kr[d2];
      float4 qq = qv4[d2];
      acc += qq.x * kv.x + qq.y * kv.y + qq.z * kv.z + qq.w * kv.w;
    }
    sc[l] = (l < nn) ? acc * 0.125f : -1e30f;
  }
  __syncthreads();
  float m = -1e30f;
  for (int l = t; l < 625; l += 256) m = fmaxf(m, sc[l]);
  red[t] = m; __syncthreads();
  for (int s2 = 128; s2 > 0; s2 >>= 1) { if (t < s2) red[t] = fmaxf(red[t], red[t + s2]); __syncthreads(); }
  m = red[0]; __syncthreads();
  float ssum = 0.f;
  for (int l = t; l < 625; l += 256) { float e = expf(sc[l] - m); sc[l] = e; ssum += e; }
  red[t] = ssum; __syncthreads();
  for (int s2 = 128; s2 > 0; s2 >>= 1) { if (t < s2) red[t] += red[t + s2]; __syncthreads(); }
  float inv = 1.f / red[0];
  __syncthreads();
  int d = t & 63, seg = t >> 6;
  float acc = 0.f;
  for (int l = seg; l < 625; l += 4) acc += sc[l] * vb[((size_t)(b * 625 + l)) * DIM + h * 64 + d];
  red[t] = acc; __syncthreads();
  if (t < 64) {
    float v = red[t] + red[64 + t] + red[128 + t] + red[192 + t];
    out[b * 256 + 128 + h * 64 + d] = v * inv;
  }
}

// sum the PBLK per-block pooled-edge partials straight into out
__global__ void gn_fin(const float* pep, float* out) {
  int i = blockIdx.x * 256 + threadIdx.x;        // 16 blocks x 256 = 4096
  float s = 0.f;
#pragma unroll 8
  for (int blk = 0; blk < PBLK; ++blk) s += pep[(size_t)blk * 4096 + i];
  int b = i >> 7, c = i & 127;
  out[b * 256 + c] = s;
}

// ---------------- launcher ----------------
extern "C" void kernel_launch(void* const* d_in, const int* in_sizes, int n_in,
                              void* d_out, int out_size, void* d_ws, size_t ws_size,
                              hipStream_t stream) {
  const float* x   = (const float*)d_in[0];
  const float* ea  = (const float*)d_in[1];
  const float* u   = (const float*)d_in[2];
  const float* qa  = (const float*)d_in[3];
  const float* We1 = (const float*)d_in[4];
  const float* be1 = (const float*)d_in[5];
  const float* We2 = (const float*)d_in[6];
  const float* be2 = (const float*)d_in[7];
  const float* Ww  = (const float*)d_in[8];
  const float* bw  = (const float*)d_in[9];
  const float* Wm1 = (const float*)d_in[10];
  const float* bm1 = (const float*)d_in[11];
  const float* Wm2 = (const float*)d_in[12];
  const float* bm2 = (const float*)d_in[13];
  const float* Wu1 = (const float*)d_in[14];
  const float* bu1 = (const float*)d_in[15];
  const float* Wu2 = (const float*)d_in[16];
  const float* bu2 = (const float*)d_in[17];
  const float* Wq  = (const float*)d_in[18];
  const float* bq  = (const float*)d_in[19];
  const float* Wk  = (const float*)d_in[20];
  const float* bk  = (const float*)d_in[21];
  const float* Wv  = (const float*)d_in[22];
  const float* bv  = (const float*)d_in[23];
  const int* ei   = (const int*)d_in[24];
  const int* nbat = (const int*)d_in[25];
  const int* non  = (const int*)d_in[26];
  float* out = (float*)d_out;

  char* p = (char*)d_ws;
  auto alloc = [&](size_t bytes) { char* r = p; p += (bytes + 255) & ~(size_t)255; return r; };
  bf16_t* EB    = (bf16_t*)alloc((size_t)NEDGE * DIM * 2);
  bf16_t* XB    = (bf16_t*)alloc((size_t)N_NODES * DIM * 2);
  bf16_t* XB0   = (bf16_t*)alloc((size_t)N_NODES * DIM * 2);
  bf16_t* MSG   = (bf16_t*)alloc((size_t)NEDGE * DIM * 2);
  bf16_t* RECVB = (bf16_t*)alloc((size_t)N_NODES * DIM * 2);
  int*   CNTI = (int*)alloc((size_t)N_NODES * 4);
  int*   OFF  = (int*)alloc((size_t)(N_NODES + 1) * 4);
  int*   CURS = (int*)alloc((size_t)N_NODES * 4);
  int*   EIDX = (int*)alloc((size_t)NEDGE * 4);
  float* WL   = (float*)alloc((size_t)NEDGE * 4);
  float* WLn  = (float*)alloc((size_t)NEDGE * 4);
  float* NW   = (float*)alloc((size_t)NEDGE * 4);
  int*   GB   = (int*)alloc((size_t)NEDGE * 4);
  float* PM   = (float*)alloc((size_t)FBLK * 32 * 4);
  float* PS   = (float*)alloc((size_t)FBLK * 32 * 4);
  float* MG   = (float*)alloc(32 * 4);
  float* SG   = (float*)alloc(32 * 4);
  float* RP   = (float*)alloc(32 * 128 * 4);
  float* UW   = (float*)alloc(32 * 4);
  bf16_t* WF  = (bf16_t*)alloc((size_t)WF_ELEMS * 2);
  float* QB   = (float*)alloc(32 * 128 * 4);
  float* KB   = (float*)alloc((size_t)N_NODES * DIM * 4);
  float* VB   = (float*)alloc((size_t)N_NODES * DIM * 4);
  float* PEP  = (float*)alloc((size_t)PBLK * 4096 * 4);
  float* PRE  = (float*)alloc((size_t)N_NODES * DIM * 4);

  hipMemsetAsync(CNTI, 0, (size_t)N_NODES * 4, stream);

  gn_xcvt<<<(N_NODES * DIM / 4 + 255) / 256, 256, 0, stream>>>(x, XB0);
  gn_fragw<<<(WF_ELEMS + 255) / 256, 256, 0, stream>>>(We1, We2, Wm1, Wm2, Wu1, Wu2, Wk, Wv, WF);
  gn_uprep<<<16, 256, 0, stream>>>(u, We1, be1, Ww, bw, RP, UW);
  gn_counti<<<1250, 256, 0, stream>>>(ei, CNTI);
  gn_scan<<<1, 256, 0, stream>>>(CNTI, OFF, CURS);
  gn_eidx<<<1250, 256, 0, stream>>>(ei, CURS, EIDX);
  gn_q<<<32, 256, 0, stream>>>(qa, Wq, bq, QB);
  gn_wl0<<<2500, 256, 0, stream>>>(ea, Ww, UW, ei, nbat, WL, GB);
  gn_part0<<<EBLK, 256, 0, stream>>>(WL, GB, PM, PS);

  for (int layer = 0; layer < 3; ++layer) {
    int first = (layer == 0) ? 1 : 0;
    int last = (layer == 2) ? 1 : 0;
    const bf16_t* xs = first ? XB0 : XB;
    const void* es = first ? (const void*)ea : (const void*)EB;
    float* cur = (layer == 1) ? WLn : WL;
    float* nxt = (layer == 1) ? WL : WLn;
    gn_reduce_ms<<<32, 256, 0, stream>>>(PM, PS, MG, SG, first ? EBLK : FBLK);
    gn_fused<<<EBLK + GPRE, 256, 0, stream>>>(xs, es, first, EB, WF, RP, UW, Ww,
                                              be2, bm1, bm2, cur, MG, SG,
                                              nxt, PM, PS, last, ei, GB, MSG,
                                              u, bu1, nbat, PRE, NW);
    gn_gather<<<5000, 256, 0, stream>>>(MSG, OFF, EIDX, RECVB);
    gn_node<<<NBLK, 64, 0, stream>>>(XB, RECVB, PRE, WF, bu2);
  }

  gn_pooled_edge<<<PBLK, 1024, 0, stream>>>(EB, NW, GB, PEP);
  gn_ev<<<dim3(NBLK, 2), 64, 0, stream>>>(XB, WF, bk, bv, KB, VB);
  gn_att<<<64, 256, 0, stream>>>(QB, KB, VB, non, out);
  gn_fin<<<16, 256, 0, stream>>>(PEP, out);
}

// Round 7
// 1333.516 us; speedup vs baseline: 1.1123x; 1.1123x over previous
//
#include <hip/hip_runtime.h>
#include <math.h>

typedef __bf16 bf16_t;
typedef bf16_t bf16x8 __attribute__((ext_vector_type(8)));
typedef bf16_t bf16x4 __attribute__((ext_vector_type(4)));
typedef bf16_t bf16x2 __attribute__((ext_vector_type(2)));
typedef float  f32x4  __attribute__((ext_vector_type(4)));

#define N_NODES 20000
#define NEDGE   320000
#define DIM     128
#define TP      136           // LDS band row stride (elems)
#define EBLK    2500          // NEDGE / 128 (fused edge blocks, 4 waves x 32 edges)
#define FBLK    10000         // NEDGE / 32  (per-wave partial count)
#define NBLK    625           // N_NODES / 32
#define GPRE    157           // ceil(20000 / 128) PRE tail blocks
#define PBLK    512           // pooled-edge blocks (4 waves each, wave-private LDS acc)

// ---- WF (MFMA b-frag-layout weights, bf16); each 128x128 chunk = 16384 elems = 32KB ----
// chunk layout: [kk 0..3][ct 0..7][lane 0..63][j 0..7]
#define FE1  0
#define FE2  49152
#define FM1  65536
#define FM2  98304
#define FU1  114688
#define FU2  163840
#define FK   180224
#define FV   196608
#define WF_ELEMS 212992

// ---------------- shared helpers ----------------
__device__ __forceinline__ void acc_zero32(f32x4 acc[2][8]) {
  f32x4 z = {0.f, 0.f, 0.f, 0.f};
#pragma unroll
  for (int i = 0; i < 2; ++i)
#pragma unroll
    for (int j = 0; j < 8; ++j) acc[i][j] = z;
}

// ---- 32-row band staging (2 lanes per row, 8x16B per lane) ----
__device__ __forceinline__ void wstage_rows_bf(bf16_t* sA, const bf16_t* src, int rowreg, int lane) {
  int r = lane >> 1, h = lane & 1;
  int row = __shfl(rowreg, r);
  const bf16_t* sp = src + (size_t)row * DIM + h * 64;
  bf16_t* dp = sA + r * TP + h * 64;
#pragma unroll
  for (int i = 0; i < 8; ++i)
    *(uint4*)(dp + i * 8) = *(const uint4*)(sp + i * 8);
}

__device__ __forceinline__ void wstage_rows_f32(bf16_t* sA, const float* src, int rowreg, int lane) {
  int r = lane >> 1, h = lane & 1;
  int row = __shfl(rowreg, r);
  const float* sp = src + (size_t)row * DIM + h * 64;
  bf16_t* dp = sA + r * TP + h * 64;
#pragma unroll
  for (int i = 0; i < 8; ++i) {
    float4 f0 = *(const float4*)(sp + i * 8);
    float4 f1 = *(const float4*)(sp + i * 8 + 4);
    bf16x8 tv;
    tv[0]=(bf16_t)f0.x; tv[1]=(bf16_t)f0.y; tv[2]=(bf16_t)f0.z; tv[3]=(bf16_t)f0.w;
    tv[4]=(bf16_t)f1.x; tv[5]=(bf16_t)f1.y; tv[6]=(bf16_t)f1.z; tv[7]=(bf16_t)f1.w;
    *(bf16x8*)(dp + i * 8) = tv;
  }
}

__device__ __forceinline__ void wstage_seq_bf(bf16_t* sA, const bf16_t* src, int base, int lane) {
  int r = lane >> 1, h = lane & 1;
  const bf16_t* sp = src + (size_t)(base + r) * DIM + h * 64;
  bf16_t* dp = sA + r * TP + h * 64;
#pragma unroll
  for (int i = 0; i < 8; ++i)
    *(uint4*)(dp + i * 8) = *(const uint4*)(sp + i * 8);
}

__device__ __forceinline__ void wstage_seq_f32(bf16_t* sA, const float* src, int base, int lane) {
  int r = lane >> 1, h = lane & 1;
  const float* sp = src + (size_t)(base + r) * DIM + h * 64;
  bf16_t* dp = sA + r * TP + h * 64;
#pragma unroll
  for (int i = 0; i < 8; ++i) {
    float4 f0 = *(const float4*)(sp + i * 8);
    float4 f1 = *(const float4*)(sp + i * 8 + 4);
    bf16x8 tv;
    tv[0]=(bf16_t)f0.x; tv[1]=(bf16_t)f0.y; tv[2]=(bf16_t)f0.z; tv[3]=(bf16_t)f0.w;
    tv[4]=(bf16_t)f1.x; tv[5]=(bf16_t)f1.y; tv[6]=(bf16_t)f1.z; tv[7]=(bf16_t)f1.w;
    *(bf16x8*)(dp + i * 8) = tv;
  }
}

// stage a full 32KB weight chunk into LDS cooperatively (256 threads x 128B) - PRE path only
__device__ __forceinline__ void chunk_stage(bf16_t* ch, const bf16_t* __restrict__ src, int t) {
#pragma unroll
  for (int i = 0; i < 8; ++i) {
    int idx = (i * 256 + t) * 8;
    *(uint4*)(ch + idx) = *(const uint4*)(src + idx);
  }
}

// one K=128 MFMA pass: A from private band, B-frags from LDS chunk
__device__ __forceinline__ void wmfma_lds(const bf16_t* sA, const bf16_t* ch,
                                          int lane, int lm, int lq, f32x4 acc[2][8]) {
#pragma unroll
  for (int kk = 0; kk < 4; ++kk) {
    int ko = kk * 32 + lq * 8;
    bf16x8 a0 = *(const bf16x8*)(sA + lm * TP + ko);
    bf16x8 a1 = *(const bf16x8*)(sA + (16 + lm) * TP + ko);
    const bf16_t* wp = ch + (kk << 12) + (lane << 3);
#pragma unroll
    for (int ct = 0; ct < 8; ++ct) {
      bf16x8 bfr = *(const bf16x8*)(wp + (ct << 9));
      acc[0][ct] = __builtin_amdgcn_mfma_f32_16x16x32_bf16(a0, bfr, acc[0][ct], 0, 0, 0);
      acc[1][ct] = __builtin_amdgcn_mfma_f32_16x16x32_bf16(a1, bfr, acc[1][ct], 0, 0, 0);
    }
  }
}

// one K=128 MFMA pass with B-frags streamed from global WF (small kernels)
__device__ __forceinline__ void wmfma_gk128(const bf16_t* sA, const bf16_t* __restrict__ Wf,
                                            int lane, int lm, int lq, f32x4 acc[2][8]) {
#pragma unroll
  for (int kk = 0; kk < 4; ++kk) {
    int ko = kk * 32 + lq * 8;
    bf16x8 a0 = *(const bf16x8*)(sA + lm * TP + ko);
    bf16x8 a1 = *(const bf16x8*)(sA + (16 + lm) * TP + ko);
    const bf16_t* wp = Wf + ((kk * 8) << 9) + (lane << 3);
#pragma unroll
    for (int ct = 0; ct < 8; ++ct) {
      bf16x8 bfr = *(const bf16x8*)(wp + (ct << 9));
      acc[0][ct] = __builtin_amdgcn_mfma_f32_16x16x32_bf16(a0, bfr, acc[0][ct], 0, 0, 0);
      acc[1][ct] = __builtin_amdgcn_mfma_f32_16x16x32_bf16(a1, bfr, acc[1][ct], 0, 0, 0);
    }
  }
}

// online-softmax merge over 2^k lanes, state (m,s)
__device__ __forceinline__ void merge_shfl(float& m, float& s, int width) {
  for (int k = 1; k < width; k <<= 1) {
    float m2 = __shfl_xor(m, k), s2 = __shfl_xor(s, k);
    float M = fmaxf(m, m2), ns = 0.f;
    if (m  > -1e29f) ns += s  * expf(m  - M);
    if (m2 > -1e29f) ns += s2 * expf(m2 - M);
    m = M; s = ns;
  }
}

// ---------------- prep kernels ----------------
__global__ void gn_xcvt(const float* x, bf16_t* xb) {
  int i = blockIdx.x * 256 + threadIdx.x;
  if (i < N_NODES * DIM / 4) {
    float4 f = ((const float4*)x)[i];
    bf16x4 o; o[0]=(bf16_t)f.x; o[1]=(bf16_t)f.y; o[2]=(bf16_t)f.z; o[3]=(bf16_t)f.w;
    *(bf16x4*)(xb + (size_t)i * 4) = o;
  }
}

__global__ void gn_fragw(const float* We1, const float* We2, const float* Wm1, const float* Wm2,
                         const float* Wu1, const float* Wu2, const float* Wk, const float* Wv,
                         bf16_t* WF) {
  int idx = blockIdx.x * 256 + threadIdx.x;
  if (idx >= WF_ELEMS) return;
  int seg = idx >> 14;
  const float* W; int kc;
  switch (seg) {
    case 0:  W = We1; kc = 0; break;
    case 1:  W = We1; kc = 1; break;
    case 2:  W = We1; kc = 2; break;
    case 3:  W = We2; kc = 0; break;
    case 4:  W = Wm1; kc = 0; break;
    case 5:  W = Wm1; kc = 1; break;
    case 6:  W = Wm2; kc = 0; break;
    case 7:  W = Wu1; kc = 0; break;
    case 8:  W = Wu1; kc = 1; break;
    case 9:  W = Wu1; kc = 2; break;
    case 10: W = Wu2; kc = 0; break;
    case 11: W = Wk;  kc = 0; break;
    default: W = Wv;  kc = 0; break;
  }
  int r = idx & 16383;
  int j = r & 7, lane = (r >> 3) & 63, ct = (r >> 9) & 7, kk = (r >> 12) & 3;
  int k = kc * 128 + kk * 32 + (lane >> 4) * 8 + j;
  int n = ct * 16 + (lane & 15);
  WF[idx] = (bf16_t)W[k * 128 + n];
}

// Rp = (u @ W_e1[384:512] + b_e1) in epilogue-transposed layout Rp[g*128 + lm*8 + ct]
// uw = u @ W_w[128:256] + b_w
__global__ void gn_uprep(const float* u, const float* We1, const float* be1,
                         const float* Ww, const float* bw, float* Rp, float* uw) {
  int t = threadIdx.x;
  for (int idx = blockIdx.x * 256 + t; idx < 32 * 128; idx += gridDim.x * 256) {
    int g = idx >> 7, c = idx & 127;
    float acc = be1[c];
    for (int k = 0; k < 128; ++k) acc += u[g * 128 + k] * We1[(384 + k) * 128 + c];
    Rp[g * 128 + (c & 15) * 8 + (c >> 4)] = acc;
  }
  if (blockIdx.x == 0 && t < 32) {
    float acc = bw[0];
    for (int k = 0; k < 128; ++k) acc += u[t * 128 + k] * Ww[128 + k];
    uw[t] = acc;
  }
}

// int in-degree count
__global__ void gn_counti(const int* ei, int* cnti) {
  int e = blockIdx.x * 256 + threadIdx.x;
  if (e < NEDGE) atomicAdd(&cnti[ei[NEDGE + e]], 1);
}

// single-block exclusive scan of cnti -> off (and cursor copy)
__global__ void gn_scan(const int* cnti, int* off, int* curs) {
  __shared__ int part[256];
  int t = threadIdx.x;
  int base = t * 80;
  int lim = base + 80; if (lim > N_NODES) lim = N_NODES;
  int s = 0;
  for (int i = base; i < lim; ++i) s += cnti[i];
  part[t] = s;
  __syncthreads();
  for (int d = 1; d < 256; d <<= 1) {
    int add = (t >= d) ? part[t - d] : 0;
    __syncthreads();
    part[t] += add;
    __syncthreads();
  }
  int pfx = (t == 0) ? 0 : part[t - 1];
  for (int i = base; i < lim; ++i) {
    off[i] = pfx; curs[i] = pfx; pfx += cnti[i];
  }
  if (t == 0) off[N_NODES] = NEDGE;
}

// scatter edge ids into CSR order by destination
__global__ void gn_eidx(const int* ei, int* curs, int* eidx) {
  int e = blockIdx.x * 256 + threadIdx.x;
  if (e < NEDGE) {
    int c = ei[NEDGE + e];
    int pos = atomicAdd(&curs[c], 1);
    eidx[pos] = e;
  }
}

__global__ void gn_q(const float* qa, const float* Wq, const float* bq, float* qb) {
  int b = blockIdx.x, t = threadIdx.x;
  int c = t & 127, half = t >> 7;
  const float* qrow = qa + b * 1024 + half * 512;
  float acc = 0.f;
  for (int k = 0; k < 512; ++k) acc += qrow[k] * Wq[(half * 512 + k) * 128 + c];
  __shared__ float red[256];
  red[t] = acc;
  __syncthreads();
  if (half == 0) qb[b * 128 + c] = red[c] + red[128 + c] + bq[c];
}

__global__ void gn_wl0(const float* ea, const float* Ww, const float* uw,
                       const int* ei, const int* nbat, float* wl, int* gb) {
  int t = threadIdx.x;
  int sub = t & 15, grp = t >> 4;
  for (int e = blockIdx.x * 16 + grp; e < NEDGE; e += gridDim.x * 16) {
    const float* er = ea + (size_t)e * DIM + sub * 8;
    float s = 0.f;
#pragma unroll
    for (int j = 0; j < 8; ++j) s += er[j] * Ww[sub * 8 + j];
#pragma unroll
    for (int m = 1; m < 16; m <<= 1) s += __shfl_xor(s, m);
    if (sub == 0) {
      int g = nbat[ei[e]];
      wl[e] = s + uw[g];
      gb[e] = g;
    }
  }
}

__global__ void gn_part0(const float* wl, const int* gb, float* pm, float* ps) {
  __shared__ float lv[128];
  __shared__ int   lgg[128];
  int t = threadIdx.x, blk = blockIdx.x, e0 = blk * 128;
  if (t < 128) { lv[t] = wl[e0 + t]; lgg[t] = gb[e0 + t]; }
  __syncthreads();
  int g = t >> 3, seg = t & 7;
  float m = -1e30f, s = 0.f;
  for (int i = seg * 16; i < seg * 16 + 16; ++i)
    if (lgg[i] == g) {
      float v = lv[i];
      if (v > m) { s = s * expf(m - v) + 1.f; m = v; }
      else s += expf(v - m);
    }
  merge_shfl(m, s, 8);
  if (seg == 0) { pm[blk * 32 + g] = m; ps[blk * 32 + g] = s; }
}

__global__ void gn_reduce_ms(const float* pm, const float* ps, float* mg, float* sg, int nb) {
  int g = blockIdx.x, t = threadIdx.x;
  __shared__ float red[256];
  float m = -1e30f;
  for (int i = t; i < nb; i += 256) m = fmaxf(m, pm[i * 32 + g]);
  red[t] = m; __syncthreads();
  for (int s2 = 128; s2 > 0; s2 >>= 1) { if (t < s2) red[t] = fmaxf(red[t], red[t + s2]); __syncthreads(); }
  m = red[0]; __syncthreads();
  float s = 0.f;
  for (int i = t; i < nb; i += 256) {
    float sb = ps[i * 32 + g];
    if (sb > 0.f) s += sb * expf(pm[i * 32 + g] - m);
  }
  red[t] = s; __syncthreads();
  for (int s2 = 128; s2 > 0; s2 >>= 1) { if (t < s2) red[t] += red[t + s2]; __syncthreads(); }
  if (t == 0) { mg[g] = m; sg[g] = red[0]; }
}

// ---------------- fused edge+message kernel ----------------
// 4 waves/block, private 32-edge bands. The 32KB weight chunk for pass p+1 is
// prefetched into REGISTERS during pass p's MFMA (T14 async-STAGE split), then
// ds_written between barriers. Barrier cost drops from L2-latency to LDS-write.
__global__ __launch_bounds__(256, 2) void gn_fused(
    const bf16_t* __restrict__ xb,
    const void* esrcv, int efirst,
    bf16_t* edst,
    const bf16_t* __restrict__ WF,
    const float* Rp, const float* UW, const float* Wwv,
    const float* be2, const float* bm1, const float* bm2,
    const float* wl_cur, const float* mg, const float* sg,
    float* wl_next, float* pm, float* ps, int last,
    const int* ei, const int* gb, bf16_t* msg,
    const float* uu, const float* bu1, const int* nbat, float* pre,
    float* nwout) {
  __shared__ bf16_t chunk[16384];
  __shared__ bf16_t band[4][32 * TP];
  __shared__ float slwt[128];

  int t = threadIdx.x;
  int w = t >> 6, lane = t & 63;
  int lm = lane & 15, lq = lane >> 4;
  int blk = blockIdx.x;
  bf16_t* myband = band[w];

  if (blk >= EBLK) {
    // ---- PRE node partial: 128 nodes per block, 32 per wave ----
    int nb128 = blk - EBLK;
    int gb32 = nb128 * 4 + w;
    int lrow = 0, lgr = 0;
    if (lane < 32) {
      int node = gb32 * 32 + lane;
      if (node > N_NODES - 1) node = N_NODES - 1;
      lrow = node;
      lgr = nbat[node];
    }
    f32x4 acc[2][8];
    acc_zero32(acc);
    wstage_rows_bf(myband, xb, lrow, lane);
    chunk_stage(chunk, WF + FU1, t);
    __syncthreads();
    wmfma_lds(myband, chunk, lane, lm, lq, acc);             // x part
    __syncthreads();
    wstage_rows_f32(myband, uu, lgr, lane);
    chunk_stage(chunk, WF + FU1 + 32768, t);
    __syncthreads();
    wmfma_lds(myband, chunk, lane, lm, lq, acc);             // u part
    if (gb32 < NBLK) {
      // coalesced layout: pre[gb32*4096 + idx*64 + lane]
      float* pp = pre + (size_t)gb32 * 4096 + lane;
#pragma unroll
      for (int rt = 0; rt < 2; ++rt)
#pragma unroll
        for (int reg = 0; reg < 4; ++reg)
#pragma unroll
          for (int ct = 0; ct < 8; ++ct)
            pp[((rt * 32 + reg * 8 + ct) << 6)] = acc[rt][ct][reg] + bu1[ct * 16 + lm];
    }
    return;
  }

  int e0 = blk * 128;
  int ew0 = e0 + w * 32;               // this wave's first edge
  int lrowr = 0, lcolr = 0, lgr = 0;
  float lnwr = 0.f;
  if (lane < 32) {
    int e = ew0 + lane;
    lrowr = ei[e];
    lcolr = ei[NEDGE + e];
    lgr = gb[e];
    lnwr = expf(wl_cur[e] - mg[lgr]) / sg[lgr];
    if (last) nwout[e] = lnwr;         // feed the pooled-edge kernel (no expf there)
  }

  f32x4 accE[2][8], accM[2][8];
  acc_zero32(accE);
  acc_zero32(accM);

  uint4 c0, c1, c2, c3, c4, c5, c6, c7;
#define CLOAD(SRC) { const uint4* _s = (const uint4*)(SRC) + t; \
  c0 = _s[0];    c1 = _s[256];  c2 = _s[512];  c3 = _s[768]; \
  c4 = _s[1024]; c5 = _s[1280]; c6 = _s[1536]; c7 = _s[1792]; }
#define CWRITE() { uint4* _d = (uint4*)chunk + t; \
  _d[0] = c0;    _d[256] = c1;  _d[512] = c2;  _d[768] = c3; \
  _d[1024] = c4; _d[1280] = c5; _d[1536] = c6; _d[1792] = c7; }

  // prologue: chunk C0 = E1c0; band B0 = x[row]
  CLOAD(WF + FE1);
  wstage_rows_bf(myband, xb, lrowr, lane);
  CWRITE();
  __syncthreads();

  // pass 0: E1c0; prefetch FM1c0
  CLOAD(WF + FM1);
  wmfma_lds(myband, chunk, lane, lm, lq, accE);
  __syncthreads();
  CWRITE();
  __syncthreads();

  // pass 1: M1c0 (same band); prefetch E1c1; restage band = x[col]
  CLOAD(WF + FE1 + 16384);
  wmfma_lds(myband, chunk, lane, lm, lq, accM);
  wstage_rows_bf(myband, xb, lcolr, lane);
  __syncthreads();
  CWRITE();
  __syncthreads();

  // pass 2: E1c1; prefetch E1c2; restage band = old edge_attr
  CLOAD(WF + FE1 + 32768);
  wmfma_lds(myband, chunk, lane, lm, lq, accE);
  if (efirst) wstage_seq_f32(myband, (const float*)esrcv, ew0, lane);
  else        wstage_seq_bf (myband, (const bf16_t*)esrcv, ew0, lane);
  __syncthreads();
  CWRITE();
  __syncthreads();

  // pass 3: E1c2; prefetch E2; epi1 hidden_e = relu(accE + Rp[g]) -> band
  CLOAD(WF + FE2);
  wmfma_lds(myband, chunk, lane, lm, lq, accE);
#pragma unroll
  for (int rt = 0; rt < 2; ++rt)
#pragma unroll
    for (int reg = 0; reg < 4; ++reg) {
      int row = rt * 16 + lq * 4 + reg;
      int g = __shfl(lgr, row);
      const float4* rp = (const float4*)(Rp + (size_t)g * 128 + lm * 8);
      float4 ra = rp[0], rb = rp[1];
      float rv[8] = {ra.x, ra.y, ra.z, ra.w, rb.x, rb.y, rb.z, rb.w};
#pragma unroll
      for (int ct = 0; ct < 8; ++ct) {
        int col = ct * 16 + lm;
        myband[row * TP + col] = (bf16_t)fmaxf(accE[rt][ct][reg] + rv[ct], 0.f);
      }
    }
  acc_zero32(accE);
  __syncthreads();
  CWRITE();
  __syncthreads();

  // pass 4: E2; prefetch M1c1; epi2 new_edge -> band + EB (vectorized) + logits
  CLOAD(WF + FM1 + 16384);
  wmfma_lds(myband, chunk, lane, lm, lq, accE);
  {
    float ww8[8], be8[8];
#pragma unroll
    for (int ct = 0; ct < 8; ++ct) { ww8[ct] = Wwv[ct * 16 + lm]; be8[ct] = be2[ct * 16 + lm]; }
#pragma unroll
    for (int rt = 0; rt < 2; ++rt)
#pragma unroll
      for (int reg = 0; reg < 4; ++reg) {
        int row = rt * 16 + lq * 4 + reg;
        int g = __shfl(lgr, row);
        float lsum = 0.f;
#pragma unroll
        for (int ct = 0; ct < 8; ++ct) {
          int col = ct * 16 + lm;
          float v = accE[rt][ct][reg] + be8[ct];
          myband[row * TP + col] = (bf16_t)v;
          lsum += v * ww8[ct];
        }
        if (!last) {
          lsum += __shfl_xor(lsum, 1);
          lsum += __shfl_xor(lsum, 2);
          lsum += __shfl_xor(lsum, 4);
          lsum += __shfl_xor(lsum, 8);
          if (lm == 0) {
            float v2 = lsum + UW[g];
            wl_next[ew0 + row] = v2;
            slwt[w * 32 + row] = v2;
          }
        }
      }
    // vectorized EB store from band (8 x uint4 per lane-pair)
    int r = lane >> 1, h = lane & 1;
    bf16_t* dp = edst + (size_t)(ew0 + r) * DIM + h * 64;
    const bf16_t* sp2 = myband + r * TP + h * 64;
#pragma unroll
    for (int i = 0; i < 8; ++i)
      *(uint4*)(dp + i * 8) = *(const uint4*)(sp2 + i * 8);
  }
  __syncthreads();
  CWRITE();
  __syncthreads();

  // pass 5: M1c1; prefetch M2; epi3 hidden_m = relu(accM + bm1) -> band
  CLOAD(WF + FM2);
  wmfma_lds(myband, chunk, lane, lm, lq, accM);
  {
    float bm18[8];
#pragma unroll
    for (int ct = 0; ct < 8; ++ct) bm18[ct] = bm1[ct * 16 + lm];
#pragma unroll
    for (int rt = 0; rt < 2; ++rt)
#pragma unroll
      for (int reg = 0; reg < 4; ++reg) {
        int row = rt * 16 + lq * 4 + reg;
#pragma unroll
        for (int ct = 0; ct < 8; ++ct) {
          int col = ct * 16 + lm;
          myband[row * TP + col] = (bf16_t)fmaxf(accM[rt][ct][reg] + bm18[ct], 0.f);
        }
      }
  }
  acc_zero32(accM);
  __syncthreads();
  CWRITE();
  __syncthreads();

  // pass 6: M2; epi4 msg -> band -> MSG (vectorized, no atomics)
  wmfma_lds(myband, chunk, lane, lm, lq, accM);
  {
    float bm28[8];
#pragma unroll
    for (int ct = 0; ct < 8; ++ct) bm28[ct] = bm2[ct * 16 + lm];
#pragma unroll
    for (int rt = 0; rt < 2; ++rt)
#pragma unroll
      for (int reg = 0; reg < 4; ++reg) {
        int row = rt * 16 + lq * 4 + reg;
        float nwv = __shfl(lnwr, row);
#pragma unroll
        for (int ct = 0; ct < 8; ++ct) {
          int col = ct * 16 + lm;
          myband[row * TP + col] = (bf16_t)((accM[rt][ct][reg] + bm28[ct]) * nwv);
        }
      }
    int r = lane >> 1, h = lane & 1;
    bf16_t* dp = msg + (size_t)(ew0 + r) * DIM + h * 64;
    const bf16_t* sp2 = myband + r * TP + h * 64;
#pragma unroll
    for (int i = 0; i < 8; ++i)
      *(uint4*)(dp + i * 8) = *(const uint4*)(sp2 + i * 8);
  }

  // per-wave softmax partials for next layer
  if (!last) {
    int g = lane >> 1, seg = lane & 1;
    float m = -1e30f, s = 0.f;
    for (int i = seg * 16; i < seg * 16 + 16; ++i) {
      int gi = __shfl(lgr, i);
      if (gi == g) {
        float v = slwt[w * 32 + i];
        if (v > m) { s = s * expf(m - v) + 1.f; m = v; }
        else s += expf(v - m);
      }
    }
    merge_shfl(m, s, 2);
    if (seg == 0) { pm[(blk * 4 + w) * 32 + g] = m; ps[(blk * 4 + w) * 32 + g] = s; }
  }
#undef CLOAD
#undef CWRITE
}

// ---------------- CSR gather: received[n] = (sum msg rows) / max(deg,1) ----------------
__global__ __launch_bounds__(256) void gn_gather(
    const bf16_t* __restrict__ msg, const int* __restrict__ off,
    const int* __restrict__ eidx, bf16_t* recvb) {
  int w = threadIdx.x >> 6, lane = threadIdx.x & 63;
  int n = blockIdx.x * 4 + w;
  int o0 = off[n], o1 = off[n + 1];
  float a0 = 0.f, a1 = 0.f;
  int i = o0;
  int e = (i < o1) ? eidx[i] : 0;
  for (; i < o1; ++i) {
    int en = (i + 1 < o1) ? eidx[i + 1] : 0;
    bf16x2 v = *(const bf16x2*)(msg + (size_t)e * DIM + lane * 2);
    a0 += (float)v[0];
    a1 += (float)v[1];
    e = en;
  }
  float ic = 1.f / fmaxf((float)(o1 - o0), 1.f);
  bf16x2 o; o[0] = (bf16_t)(a0 * ic); o[1] = (bf16_t)(a1 * ic);
  *(bf16x2*)(recvb + (size_t)n * DIM + lane * 2) = o;
}

// ---------------- node update POST kernel ----------------
__global__ __launch_bounds__(64, 3) void gn_node(
    bf16_t* xdst, const bf16_t* recvb, const float* pre,
    const bf16_t* __restrict__ WF, const float* bu2) {
  __shared__ bf16_t sA[32 * TP];

  int lane = threadIdx.x;
  int nb = blockIdx.x;
  int n0 = nb * 32;
  int lm = lane & 15, lq = lane >> 4;

  wstage_seq_bf(sA, recvb, n0, lane);

  f32x4 acc[2][8];
  acc_zero32(acc);
  wmfma_gk128(sA, WF + FU1 + 16384, lane, lm, lq, acc);      // received part

  // hidden_u = relu(acc + PRE)  (coalesced layout: pre[nb*4096 + idx*64 + lane])
  const float* pp = pre + (size_t)nb * 4096 + lane;
#pragma unroll
  for (int rt = 0; rt < 2; ++rt)
#pragma unroll
    for (int reg = 0; reg < 4; ++reg) {
      int row = rt * 16 + lq * 4 + reg;
#pragma unroll
      for (int ct = 0; ct < 8; ++ct) {
        int col = ct * 16 + lm;
        sA[row * TP + col] = (bf16_t)fmaxf(acc[rt][ct][reg] + pp[((rt * 32 + reg * 8 + ct) << 6)], 0.f);
      }
    }
  acc_zero32(acc);
  wmfma_gk128(sA, WF + FU2, lane, lm, lq, acc);

  {
    float bu28[8];
#pragma unroll
    for (int ct = 0; ct < 8; ++ct) bu28[ct] = bu2[ct * 16 + lm];
#pragma unroll
    for (int rt = 0; rt < 2; ++rt)
#pragma unroll
      for (int reg = 0; reg < 4; ++reg) {
        int row = rt * 16 + lq * 4 + reg;
        bf16_t* dr = xdst + (size_t)(n0 + row) * DIM;
#pragma unroll
        for (int ct = 0; ct < 8; ++ct) {
          int col = ct * 16 + lm;
          dr[col] = (bf16_t)(acc[rt][ct][reg] + bu28[ct]);
        }
      }
  }
}

// ---------------- evidence -> K/V projection ----------------
__global__ __launch_bounds__(64, 3) void gn_ev(
    const bf16_t* xsrc, const bf16_t* __restrict__ WF,
    const float* bk, const float* bv, float* kb, float* vb) {
  __shared__ bf16_t sA[32 * TP];

  int lane = threadIdx.x;
  int n0 = blockIdx.x * 32;
  int sel = blockIdx.y;
  const bf16_t* Wf = WF + (sel ? FV : FK);
  const float* bias = sel ? bv : bk;
  float* dst = sel ? vb : kb;
  int lm = lane & 15, lq = lane >> 4;

  {
    int r = lane >> 1, h = lane & 1;
    const bf16_t* sp = xsrc + (size_t)(n0 + r) * DIM + h * 64;
    bf16_t* dp = sA + r * TP + h * 64;
#pragma unroll
    for (int i = 0; i < 8; ++i) {
      uint4 v = *(const uint4*)(sp + i * 8);
      bf16_t tmp[8];
      *(uint4*)tmp = v;
      bf16x8 tv;
#pragma unroll
      for (int j = 0; j < 8; ++j) {
        float f = (float)tmp[j];
        tv[j] = (bf16_t)(0.5f * f * (1.f + erff(f * 0.70710678118654752f)));
      }
      *(bf16x8*)(dp + i * 8) = tv;
    }
  }

  f32x4 acc[2][8];
  acc_zero32(acc);
  wmfma_gk128(sA, Wf, lane, lm, lq, acc);

  {
    float b8[8];
#pragma unroll
    for (int ct = 0; ct < 8; ++ct) b8[ct] = bias[ct * 16 + lm];
#pragma unroll
    for (int rt = 0; rt < 2; ++rt)
#pragma unroll
      for (int reg = 0; reg < 4; ++reg) {
        int row = rt * 16 + lq * 4 + reg;
        float* dr = dst + (size_t)(n0 + row) * DIM;
#pragma unroll
        for (int ct = 0; ct < 8; ++ct) {
          int col = ct * 16 + lm;
          dr[col] = acc[rt][ct][reg] + b8[ct];
        }
      }
  }
}

// ---------------- pooled edge: wave-private LDS accumulators, NO atomics ----------------
// 4 waves/block, each wave owns loc[w][4096]; lane l owns cols 2l/2l+1 -> no collisions.
__global__ __launch_bounds__(256, 2) void gn_pooled_edge(
    const bf16_t* __restrict__ eb, const float* __restrict__ nw,
    const int* __restrict__ gb, float* pep) {
  __shared__ float loc[4][4096];
  int t = threadIdx.x;
  int lane = t & 63, w = t >> 6;
  float* myloc = loc[w];
  for (int i = lane; i < 4096; i += 64) myloc[i] = 0.f;
  // no barrier: each wave touches only its own buffer until the final merge

  int wid = blockIdx.x * 4 + w;                 // PBLK*4 = 2048 waves
  int c0 = lane * 2;
  for (int e = wid; e < NEDGE; e += PBLK * 4) {
    int g = gb[e];
    float nwt = nw[e];
    bf16x2 v = *(const bf16x2*)(eb + (size_t)e * DIM + c0);
    float* a = myloc + g * 128 + c0;
    float2 cur = *(float2*)a;
    cur.x += (float)v[0] * nwt;
    cur.y += (float)v[1] * nwt;
    *(float2*)a = cur;
  }
  __syncthreads();
  float* pp = pep + (size_t)blockIdx.x * 4096;
  for (int i = t; i < 4096; i += 256)
    pp[i] = loc[0][i] + loc[1][i] + loc[2][i] + loc[3][i];
}

// ---------------- attention pool ----------------
__global__ void gn_att(const float* qb, const float* kb, const float* vb, const int* non, float* out) {
  int b = blockIdx.x >> 1, h = blockIdx.x & 1, t = threadIdx.x;
  __shared__ float qv[64];
  __shared__ float sc[625];
  __shared__ float red[256];
  if (t < 64) qv[t] = qb[b * 128 + h * 64 + t];
  __syncthreads();
  int nn = non[b];
  const float4* qv4 = (const float4*)qv;
  for (int l = t; l < 625; l += 256) {
    float acc = 0.f;
    const float4* kr = (const float4*)(kb + ((size_t)(b * 625 + l)) * DIM + h * 64);
#pragma unroll
    for (int d2 = 0; d2 < 16; ++d2) {
      float4 kv = kr[d2];
      float4 qq = qv4[d2];
      acc += qq.x * kv.x + qq.y * kv.y + qq.z * kv.z + qq.w * kv.w;
    }
    sc[l] = (l < nn) ? acc * 0.125f : -1e30f;
  }
  __syncthreads();
  float m = -1e30f;
  for (int l = t; l < 625; l += 256) m = fmaxf(m, sc[l]);
  red[t] = m; __syncthreads();
  for (int s2 = 128; s2 > 0; s2 >>= 1) { if (t < s2) red[t] = fmaxf(red[t], red[t + s2]); __syncthreads(); }
  m = red[0]; __syncthreads();
  float ssum = 0.f;
  for (int l = t; l < 625; l += 256) { float e = expf(sc[l] - m); sc[l] = e; ssum += e; }
  red[t] = ssum; __syncthreads();
  for (int s2 = 128; s2 > 0; s2 >>= 1) { if (t < s2) red[t] += red[t + s2]; __syncthreads(); }
  float inv = 1.f / red[0];
  __syncthreads();
  int d = t & 63, seg = t >> 6;
  float acc = 0.f;
  for (int l = seg; l < 625; l += 4) acc += sc[l] * vb[((size_t)(b * 625 + l)) * DIM + h * 64 + d];
  red[t] = acc; __syncthreads();
  if (t < 64) {
    float v = red[t] + red[64 + t] + red[128 + t] + red[192 + t];
    out[b * 256 + 128 + h * 64 + d] = v * inv;
  }
}

// sum the PBLK per-block pooled-edge partials straight into out
__global__ void gn_fin(const float* pep, float* out) {
  int i = blockIdx.x * 256 + threadIdx.x;        // 16 blocks x 256 = 4096
  float s = 0.f;
#pragma unroll 8
  for (int blk = 0; blk < PBLK; ++blk) s += pep[(size_t)blk * 4096 + i];
  int b = i >> 7, c = i & 127;
  out[b * 256 + c] = s;
}

// ---------------- launcher ----------------
extern "C" void kernel_launch(void* const* d_in, const int* in_sizes, int n_in,
                              void* d_out, int out_size, void* d_ws, size_t ws_size,
                              hipStream_t stream) {
  const float* x   = (const float*)d_in[0];
  const float* ea  = (const float*)d_in[1];
  const float* u   = (const float*)d_in[2];
  const float* qa  = (const float*)d_in[3];
  const float* We1 = (const float*)d_in[4];
  const float* be1 = (const float*)d_in[5];
  const float* We2 = (const float*)d_in[6];
  const float* be2 = (const float*)d_in[7];
  const float* Ww  = (const float*)d_in[8];
  const float* bw  = (const float*)d_in[9];
  const float* Wm1 = (const float*)d_in[10];
  const float* bm1 = (const float*)d_in[11];
  const float* Wm2 = (const float*)d_in[12];
  const float* bm2 = (const float*)d_in[13];
  const float* Wu1 = (const float*)d_in[14];
  const float* bu1 = (const float*)d_in[15];
  const float* Wu2 = (const float*)d_in[16];
  const float* bu2 = (const float*)d_in[17];
  const float* Wq  = (const float*)d_in[18];
  const float* bq  = (const float*)d_in[19];
  const float* Wk  = (const float*)d_in[20];
  const float* bk  = (const float*)d_in[21];
  const float* Wv  = (const float*)d_in[22];
  const float* bv  = (const float*)d_in[23];
  const int* ei   = (const int*)d_in[24];
  const int* nbat = (const int*)d_in[25];
  const int* non  = (const int*)d_in[26];
  float* out = (float*)d_out;

  char* p = (char*)d_ws;
  auto alloc = [&](size_t bytes) { char* r = p; p += (bytes + 255) & ~(size_t)255; return r; };
  bf16_t* EB    = (bf16_t*)alloc((size_t)NEDGE * DIM * 2);
  bf16_t* XB    = (bf16_t*)alloc((size_t)N_NODES * DIM * 2);
  bf16_t* XB0   = (bf16_t*)alloc((size_t)N_NODES * DIM * 2);
  bf16_t* MSG   = (bf16_t*)alloc((size_t)NEDGE * DIM * 2);
  bf16_t* RECVB = (bf16_t*)alloc((size_t)N_NODES * DIM * 2);
  int*   CNTI = (int*)alloc((size_t)N_NODES * 4);
  int*   OFF  = (int*)alloc((size_t)(N_NODES + 1) * 4);
  int*   CURS = (int*)alloc((size_t)N_NODES * 4);
  int*   EIDX = (int*)alloc((size_t)NEDGE * 4);
  float* WL   = (float*)alloc((size_t)NEDGE * 4);
  float* WLn  = (float*)alloc((size_t)NEDGE * 4);
  float* NW   = (float*)alloc((size_t)NEDGE * 4);
  int*   GB   = (int*)alloc((size_t)NEDGE * 4);
  float* PM   = (float*)alloc((size_t)FBLK * 32 * 4);
  float* PS   = (float*)alloc((size_t)FBLK * 32 * 4);
  float* MG   = (float*)alloc(32 * 4);
  float* SG   = (float*)alloc(32 * 4);
  float* RP   = (float*)alloc(32 * 128 * 4);
  float* UW   = (float*)alloc(32 * 4);
  bf16_t* WF  = (bf16_t*)alloc((size_t)WF_ELEMS * 2);
  float* QB   = (float*)alloc(32 * 128 * 4);
  float* KB   = (float*)alloc((size_t)N_NODES * DIM * 4);
  float* VB   = (float*)alloc((size_t)N_NODES * DIM * 4);
  float* PEP  = (float*)alloc((size_t)PBLK * 4096 * 4);
  float* PRE  = (float*)alloc((size_t)N_NODES * DIM * 4);

  hipMemsetAsync(CNTI, 0, (size_t)N_NODES * 4, stream);

  gn_xcvt<<<(N_NODES * DIM / 4 + 255) / 256, 256, 0, stream>>>(x, XB0);
  gn_fragw<<<(WF_ELEMS + 255) / 256, 256, 0, stream>>>(We1, We2, Wm1, Wm2, Wu1, Wu2, Wk, Wv, WF);
  gn_uprep<<<16, 256, 0, stream>>>(u, We1, be1, Ww, bw, RP, UW);
  gn_counti<<<1250, 256, 0, stream>>>(ei, CNTI);
  gn_scan<<<1, 256, 0, stream>>>(CNTI, OFF, CURS);
  gn_eidx<<<1250, 256, 0, stream>>>(ei, CURS, EIDX);
  gn_q<<<32, 256, 0, stream>>>(qa, Wq, bq, QB);
  gn_wl0<<<2500, 256, 0, stream>>>(ea, Ww, UW, ei, nbat, WL, GB);
  gn_part0<<<EBLK, 256, 0, stream>>>(WL, GB, PM, PS);

  for (int layer = 0; layer < 3; ++layer) {
    int first = (layer == 0) ? 1 : 0;
    int last = (layer == 2) ? 1 : 0;
    const bf16_t* xs = first ? XB0 : XB;
    const void* es = first ? (const void*)ea : (const void*)EB;
    float* cur = (layer == 1) ? WLn : WL;
    float* nxt = (layer == 1) ? WL : WLn;
    gn_reduce_ms<<<32, 256, 0, stream>>>(PM, PS, MG, SG, first ? EBLK : FBLK);
    gn_fused<<<EBLK + GPRE, 256, 0, stream>>>(xs, es, first, EB, WF, RP, UW, Ww,
                                              be2, bm1, bm2, cur, MG, SG,
                                              nxt, PM, PS, last, ei, GB, MSG,
                                              u, bu1, nbat, PRE, NW);
    gn_gather<<<5000, 256, 0, stream>>>(MSG, OFF, EIDX, RECVB);
    gn_node<<<NBLK, 64, 0, stream>>>(XB, RECVB, PRE, WF, bu2);
  }

  gn_pooled_edge<<<PBLK, 256, 0, stream>>>(EB, NW, GB, PEP);
  gn_ev<<<dim3(NBLK, 2), 64, 0, stream>>>(XB, WF, bk, bv, KB, VB);
  gn_att<<<64, 256, 0, stream>>>(QB, KB, VB, non, out);
  gn_fin<<<16, 256, 0, stream>>>(PEP, out);
}

// Round 8
// 1319.594 us; speedup vs baseline: 1.1240x; 1.0106x over previous
//
#include <hip/hip_runtime.h>
#include <math.h>

typedef __bf16 bf16_t;
typedef bf16_t bf16x8 __attribute__((ext_vector_type(8)));
typedef bf16_t bf16x4 __attribute__((ext_vector_type(4)));
typedef bf16_t bf16x2 __attribute__((ext_vector_type(2)));
typedef float  f32x4  __attribute__((ext_vector_type(4)));

#define N_NODES 20000
#define NEDGE   320000
#define DIM     128
#define TP      136           // LDS band row stride (elems)
#define EBLK    2500          // NEDGE / 128 (fused edge blocks, 4 waves x 32 edges)
#define FWAVES  10000         // NEDGE / 32  (per-wave partial count)
#define NBLK    625           // N_NODES / 32
#define GPRE    157           // ceil(20000 / 128) PRE tail blocks
#define PBLK    512           // pooled-edge blocks (4 waves each, wave-private LDS acc)

// ---- WF (MFMA b-frag-layout weights, bf16); each 128x128 chunk = 16384 elems = 32KB ----
// chunk layout: [kk 0..3][ct 0..7][lane 0..63][j 0..7]
#define FE1  0
#define FE2  49152
#define FM1  65536
#define FM2  98304            // unused after M2-fold (kept for layout stability)
#define FU1  114688
#define FU2  163840
#define FK   180224
#define FV   196608
#define FWC  212992           // Wcomb = Wm2 @ Wu1[128:256]
#define WF_ELEMS 229376       // 14 * 16384

// ---------------- shared helpers ----------------
__device__ __forceinline__ void acc_zero32(f32x4 acc[2][8]) {
  f32x4 z = {0.f, 0.f, 0.f, 0.f};
#pragma unroll
  for (int i = 0; i < 2; ++i)
#pragma unroll
    for (int j = 0; j < 8; ++j) acc[i][j] = z;
}

// ---- 32-row band staging (2 lanes per row, 8x16B per lane) ----
__device__ __forceinline__ void wstage_rows_bf(bf16_t* sA, const bf16_t* src, int rowreg, int lane) {
  int r = lane >> 1, h = lane & 1;
  int row = __shfl(rowreg, r);
  const bf16_t* sp = src + (size_t)row * DIM + h * 64;
  bf16_t* dp = sA + r * TP + h * 64;
#pragma unroll
  for (int i = 0; i < 8; ++i)
    *(uint4*)(dp + i * 8) = *(const uint4*)(sp + i * 8);
}

__device__ __forceinline__ void wstage_rows_f32(bf16_t* sA, const float* src, int rowreg, int lane) {
  int r = lane >> 1, h = lane & 1;
  int row = __shfl(rowreg, r);
  const float* sp = src + (size_t)row * DIM + h * 64;
  bf16_t* dp = sA + r * TP + h * 64;
#pragma unroll
  for (int i = 0; i < 8; ++i) {
    float4 f0 = *(const float4*)(sp + i * 8);
    float4 f1 = *(const float4*)(sp + i * 8 + 4);
    bf16x8 tv;
    tv[0]=(bf16_t)f0.x; tv[1]=(bf16_t)f0.y; tv[2]=(bf16_t)f0.z; tv[3]=(bf16_t)f0.w;
    tv[4]=(bf16_t)f1.x; tv[5]=(bf16_t)f1.y; tv[6]=(bf16_t)f1.z; tv[7]=(bf16_t)f1.w;
    *(bf16x8*)(dp + i * 8) = tv;
  }
}

__device__ __forceinline__ void wstage_seq_bf(bf16_t* sA, const bf16_t* src, int base, int lane) {
  int r = lane >> 1, h = lane & 1;
  const bf16_t* sp = src + (size_t)(base + r) * DIM + h * 64;
  bf16_t* dp = sA + r * TP + h * 64;
#pragma unroll
  for (int i = 0; i < 8; ++i)
    *(uint4*)(dp + i * 8) = *(const uint4*)(sp + i * 8);
}

__device__ __forceinline__ void wstage_seq_f32(bf16_t* sA, const float* src, int base, int lane) {
  int r = lane >> 1, h = lane & 1;
  const float* sp = src + (size_t)(base + r) * DIM + h * 64;
  bf16_t* dp = sA + r * TP + h * 64;
#pragma unroll
  for (int i = 0; i < 8; ++i) {
    float4 f0 = *(const float4*)(sp + i * 8);
    float4 f1 = *(const float4*)(sp + i * 8 + 4);
    bf16x8 tv;
    tv[0]=(bf16_t)f0.x; tv[1]=(bf16_t)f0.y; tv[2]=(bf16_t)f0.z; tv[3]=(bf16_t)f0.w;
    tv[4]=(bf16_t)f1.x; tv[5]=(bf16_t)f1.y; tv[6]=(bf16_t)f1.z; tv[7]=(bf16_t)f1.w;
    *(bf16x8*)(dp + i * 8) = tv;
  }
}

// stage a full 32KB weight chunk into LDS cooperatively (256 threads x 128B) - PRE path only
__device__ __forceinline__ void chunk_stage(bf16_t* ch, const bf16_t* __restrict__ src, int t) {
#pragma unroll
  for (int i = 0; i < 8; ++i) {
    int idx = (i * 256 + t) * 8;
    *(uint4*)(ch + idx) = *(const uint4*)(src + idx);
  }
}

// one K=128 MFMA pass: A from private band, B-frags from LDS chunk
__device__ __forceinline__ void wmfma_lds(const bf16_t* sA, const bf16_t* ch,
                                          int lane, int lm, int lq, f32x4 acc[2][8]) {
#pragma unroll
  for (int kk = 0; kk < 4; ++kk) {
    int ko = kk * 32 + lq * 8;
    bf16x8 a0 = *(const bf16x8*)(sA + lm * TP + ko);
    bf16x8 a1 = *(const bf16x8*)(sA + (16 + lm) * TP + ko);
    const bf16_t* wp = ch + (kk << 12) + (lane << 3);
#pragma unroll
    for (int ct = 0; ct < 8; ++ct) {
      bf16x8 bfr = *(const bf16x8*)(wp + (ct << 9));
      acc[0][ct] = __builtin_amdgcn_mfma_f32_16x16x32_bf16(a0, bfr, acc[0][ct], 0, 0, 0);
      acc[1][ct] = __builtin_amdgcn_mfma_f32_16x16x32_bf16(a1, bfr, acc[1][ct], 0, 0, 0);
    }
  }
}

// one K=128 MFMA pass with B-frags streamed from global WF (small kernels)
__device__ __forceinline__ void wmfma_gk128(const bf16_t* sA, const bf16_t* __restrict__ Wf,
                                            int lane, int lm, int lq, f32x4 acc[2][8]) {
#pragma unroll
  for (int kk = 0; kk < 4; ++kk) {
    int ko = kk * 32 + lq * 8;
    bf16x8 a0 = *(const bf16x8*)(sA + lm * TP + ko);
    bf16x8 a1 = *(const bf16x8*)(sA + (16 + lm) * TP + ko);
    const bf16_t* wp = Wf + ((kk * 8) << 9) + (lane << 3);
#pragma unroll
    for (int ct = 0; ct < 8; ++ct) {
      bf16x8 bfr = *(const bf16x8*)(wp + (ct << 9));
      acc[0][ct] = __builtin_amdgcn_mfma_f32_16x16x32_bf16(a0, bfr, acc[0][ct], 0, 0, 0);
      acc[1][ct] = __builtin_amdgcn_mfma_f32_16x16x32_bf16(a1, bfr, acc[1][ct], 0, 0, 0);
    }
  }
}

// online-softmax merge over 2^k lanes, state (m,s)
__device__ __forceinline__ void merge_shfl(float& m, float& s, int width) {
  for (int k = 1; k < width; k <<= 1) {
    float m2 = __shfl_xor(m, k), s2 = __shfl_xor(s, k);
    float M = fmaxf(m, m2), ns = 0.f;
    if (m  > -1e29f) ns += s  * expf(m  - M);
    if (m2 > -1e29f) ns += s2 * expf(m2 - M);
    m = M; s = ns;
  }
}

// ---------------- prep kernels ----------------
__global__ void gn_xcvt(const float* x, bf16_t* xb) {
  int i = blockIdx.x * 256 + threadIdx.x;
  if (i < N_NODES * DIM / 4) {
    float4 f = ((const float4*)x)[i];
    bf16x4 o; o[0]=(bf16_t)f.x; o[1]=(bf16_t)f.y; o[2]=(bf16_t)f.z; o[3]=(bf16_t)f.w;
    *(bf16x4*)(xb + (size_t)i * 4) = o;
  }
}

// Wcomb = Wm2 @ Wu1[128:256]  (f32, 128x128)
__global__ void gn_wcomb(const float* Wm2, const float* Wu1, float* wc) {
  int idx = blockIdx.x * 256 + threadIdx.x;
  if (idx >= 16384) return;
  int i = idx >> 7, j = idx & 127;
  float acc = 0.f;
  for (int m = 0; m < 128; ++m)
    acc += Wm2[i * 128 + m] * Wu1[(128 + m) * 128 + j];
  wc[idx] = acc;
}

__global__ void gn_fragw(const float* We1, const float* We2, const float* Wm1, const float* Wm2,
                         const float* Wu1, const float* Wu2, const float* Wk, const float* Wv,
                         const float* Wc, bf16_t* WF) {
  int idx = blockIdx.x * 256 + threadIdx.x;
  if (idx >= WF_ELEMS) return;
  int seg = idx >> 14;
  const float* W; int kc;
  switch (seg) {
    case 0:  W = We1; kc = 0; break;
    case 1:  W = We1; kc = 1; break;
    case 2:  W = We1; kc = 2; break;
    case 3:  W = We2; kc = 0; break;
    case 4:  W = Wm1; kc = 0; break;
    case 5:  W = Wm1; kc = 1; break;
    case 6:  W = Wm2; kc = 0; break;
    case 7:  W = Wu1; kc = 0; break;
    case 8:  W = Wu1; kc = 1; break;
    case 9:  W = Wu1; kc = 2; break;
    case 10: W = Wu2; kc = 0; break;
    case 11: W = Wk;  kc = 0; break;
    case 12: W = Wv;  kc = 0; break;
    default: W = Wc;  kc = 0; break;
  }
  int r = idx & 16383;
  int j = r & 7, lane = (r >> 3) & 63, ct = (r >> 9) & 7, kk = (r >> 12) & 3;
  int k = kc * 128 + kk * 32 + (lane >> 4) * 8 + j;
  int n = ct * 16 + (lane & 15);
  WF[idx] = (bf16_t)W[k * 128 + n];
}

// Rp = (u @ W_e1[384:512] + b_e1) transposed layout; uw = u @ W_w[128:256] + b_w;
// bm2u = bm2 @ Wu1[128:256]
__global__ void gn_uprep(const float* u, const float* We1, const float* be1,
                         const float* Ww, const float* bw,
                         const float* bm2, const float* Wu1,
                         float* Rp, float* uw, float* bm2u) {
  int t = threadIdx.x;
  for (int idx = blockIdx.x * 256 + t; idx < 32 * 128; idx += gridDim.x * 256) {
    int g = idx >> 7, c = idx & 127;
    float acc = be1[c];
    for (int k = 0; k < 128; ++k) acc += u[g * 128 + k] * We1[(384 + k) * 128 + c];
    Rp[g * 128 + (c & 15) * 8 + (c >> 4)] = acc;
  }
  if (blockIdx.x == 0 && t < 32) {
    float acc = bw[0];
    for (int k = 0; k < 128; ++k) acc += u[t * 128 + k] * Ww[128 + k];
    uw[t] = acc;
  }
  if (blockIdx.x == 1 && t < 128) {
    float acc = 0.f;
    for (int k = 0; k < 128; ++k) acc += bm2[k] * Wu1[(128 + k) * 128 + t];
    bm2u[t] = acc;
  }
}

// int in-degree count
__global__ void gn_counti(const int* ei, int* cnti) {
  int e = blockIdx.x * 256 + threadIdx.x;
  if (e < NEDGE) atomicAdd(&cnti[ei[NEDGE + e]], 1);
}

// single-block exclusive scan of cnti -> off (and cursor copy)
__global__ void gn_scan(const int* cnti, int* off, int* curs) {
  __shared__ int part[256];
  int t = threadIdx.x;
  int base = t * 80;
  int lim = base + 80; if (lim > N_NODES) lim = N_NODES;
  int s = 0;
  for (int i = base; i < lim; ++i) s += cnti[i];
  part[t] = s;
  __syncthreads();
  for (int d = 1; d < 256; d <<= 1) {
    int add = (t >= d) ? part[t - d] : 0;
    __syncthreads();
    part[t] += add;
    __syncthreads();
  }
  int pfx = (t == 0) ? 0 : part[t - 1];
  for (int i = base; i < lim; ++i) {
    off[i] = pfx; curs[i] = pfx; pfx += cnti[i];
  }
  if (t == 0) off[N_NODES] = NEDGE;
}

// scatter edge ids into CSR order by destination
__global__ void gn_eidx(const int* ei, int* curs, int* eidx) {
  int e = blockIdx.x * 256 + threadIdx.x;
  if (e < NEDGE) {
    int c = ei[NEDGE + e];
    int pos = atomicAdd(&curs[c], 1);
    eidx[pos] = e;
  }
}

__global__ void gn_q(const float* qa, const float* Wq, const float* bq, float* qb) {
  int b = blockIdx.x, t = threadIdx.x;
  int c = t & 127, half = t >> 7;
  const float* qrow = qa + b * 1024 + half * 512;
  float acc = 0.f;
  for (int k = 0; k < 512; ++k) acc += qrow[k] * Wq[(half * 512 + k) * 128 + c];
  __shared__ float red[256];
  red[t] = acc;
  __syncthreads();
  if (half == 0) qb[b * 128 + c] = red[c] + red[128 + c] + bq[c];
}

__global__ void gn_wl0(const float* ea, const float* Ww, const float* uw,
                       const int* ei, const int* nbat, float* wl, int* gb) {
  int t = threadIdx.x;
  int sub = t & 15, grp = t >> 4;
  for (int e = blockIdx.x * 16 + grp; e < NEDGE; e += gridDim.x * 16) {
    const float* er = ea + (size_t)e * DIM + sub * 8;
    float s = 0.f;
#pragma unroll
    for (int j = 0; j < 8; ++j) s += er[j] * Ww[sub * 8 + j];
#pragma unroll
    for (int m = 1; m < 16; m <<= 1) s += __shfl_xor(s, m);
    if (sub == 0) {
      int g = nbat[ei[e]];
      wl[e] = s + uw[g];
      gb[e] = g;
    }
  }
}

// per-128-edge-block softmax partials, layer 0.  pm layout: [g][wave] coalesced.
__global__ void gn_part0(const float* wl, const int* gb, float* pm, float* ps) {
  __shared__ float lv[128];
  __shared__ int   lgg[128];
  int t = threadIdx.x, blk = blockIdx.x, e0 = blk * 128;
  if (t < 128) { lv[t] = wl[e0 + t]; lgg[t] = gb[e0 + t]; }
  __syncthreads();
  int g = t >> 3, seg = t & 7;
  float m = -1e30f, s = 0.f;
  for (int i = seg * 16; i < seg * 16 + 16; ++i)
    if (lgg[i] == g) {
      float v = lv[i];
      if (v > m) { s = s * expf(m - v) + 1.f; m = v; }
      else s += expf(v - m);
    }
  merge_shfl(m, s, 8);
  if (seg == 0) { pm[g * FWAVES + blk] = m; ps[g * FWAVES + blk] = s; }
}

__global__ void gn_reduce_ms(const float* pm, const float* ps, float* mg, float* sg, int nb) {
  int g = blockIdx.x, t = threadIdx.x;
  __shared__ float red[256];
  float m = -1e30f;
  for (int i = t; i < nb; i += 256) m = fmaxf(m, pm[g * FWAVES + i]);
  red[t] = m; __syncthreads();
  for (int s2 = 128; s2 > 0; s2 >>= 1) { if (t < s2) red[t] = fmaxf(red[t], red[t + s2]); __syncthreads(); }
  m = red[0]; __syncthreads();
  float s = 0.f;
  for (int i = t; i < nb; i += 256) {
    float sb = ps[g * FWAVES + i];
    if (sb > 0.f) s += sb * expf(pm[g * FWAVES + i] - m);
  }
  red[t] = s; __syncthreads();
  for (int s2 = 128; s2 > 0; s2 >>= 1) { if (t < s2) red[t] += red[t + s2]; __syncthreads(); }
  if (t == 0) { mg[g] = m; sg[g] = red[0]; }
}

// ---------------- fused edge+message kernel (6 passes; M2 folded out) ----------------
// 4 waves/block, private 32-edge bands; 32KB chunk register-prefetched (T14).
// MSG now carries h_m * nw (pre-M2); M2 is folded into gn_node via Wcomb.
__global__ __launch_bounds__(256, 2) void gn_fused(
    const bf16_t* __restrict__ xb,
    const void* esrcv, int efirst,
    bf16_t* edst,
    const bf16_t* __restrict__ WF,
    const float* Rp, const float* UW, const float* Wwv,
    const float* be2, const float* bm1,
    const float* wl_cur, const float* mg, const float* sg,
    float* wl_next, float* pm, float* ps, int last,
    const int* ei, const int* gb, bf16_t* msg,
    const float* uu, const float* bu1, const int* nbat, float* pre,
    float* nwout) {
  __shared__ bf16_t chunk[16384];
  __shared__ bf16_t band[4][32 * TP];
  __shared__ float slwt[128];

  int t = threadIdx.x;
  int w = t >> 6, lane = t & 63;
  int lm = lane & 15, lq = lane >> 4;
  int blk = blockIdx.x;
  bf16_t* myband = band[w];

  if (blk >= EBLK) {
    // ---- PRE node partial: 128 nodes per block, 32 per wave ----
    int nb128 = blk - EBLK;
    int gb32 = nb128 * 4 + w;
    int lrow = 0, lgr = 0;
    if (lane < 32) {
      int node = gb32 * 32 + lane;
      if (node > N_NODES - 1) node = N_NODES - 1;
      lrow = node;
      lgr = nbat[node];
    }
    f32x4 acc[2][8];
    acc_zero32(acc);
    wstage_rows_bf(myband, xb, lrow, lane);
    chunk_stage(chunk, WF + FU1, t);
    __syncthreads();
    wmfma_lds(myband, chunk, lane, lm, lq, acc);             // x part
    __syncthreads();
    wstage_rows_f32(myband, uu, lgr, lane);
    chunk_stage(chunk, WF + FU1 + 32768, t);
    __syncthreads();
    wmfma_lds(myband, chunk, lane, lm, lq, acc);             // u part
    if (gb32 < NBLK) {
      float* pp = pre + (size_t)gb32 * 4096 + lane;
#pragma unroll
      for (int rt = 0; rt < 2; ++rt)
#pragma unroll
        for (int reg = 0; reg < 4; ++reg)
#pragma unroll
          for (int ct = 0; ct < 8; ++ct)
            pp[((rt * 32 + reg * 8 + ct) << 6)] = acc[rt][ct][reg] + bu1[ct * 16 + lm];
    }
    return;
  }

  int e0 = blk * 128;
  int ew0 = e0 + w * 32;               // this wave's first edge
  int lrowr = 0, lcolr = 0, lgr = 0;
  float lnwr = 0.f;
  if (lane < 32) {
    int e = ew0 + lane;
    lrowr = ei[e];
    lcolr = ei[NEDGE + e];
    lgr = gb[e];
    lnwr = expf(wl_cur[e] - mg[lgr]) / sg[lgr];
    nwout[e] = lnwr;                   // consumed by gather (snw) & final pooled-edge
  }

  f32x4 accE[2][8], accM[2][8];
  acc_zero32(accE);
  acc_zero32(accM);

  uint4 c0, c1, c2, c3, c4, c5, c6, c7;
#define CLOAD(SRC) { const uint4* _s = (const uint4*)(SRC) + t; \
  c0 = _s[0];    c1 = _s[256];  c2 = _s[512];  c3 = _s[768]; \
  c4 = _s[1024]; c5 = _s[1280]; c6 = _s[1536]; c7 = _s[1792]; }
#define CWRITE() { uint4* _d = (uint4*)chunk + t; \
  _d[0] = c0;    _d[256] = c1;  _d[512] = c2;  _d[768] = c3; \
  _d[1024] = c4; _d[1280] = c5; _d[1536] = c6; _d[1792] = c7; }

  // prologue: chunk C0 = E1c0; band B0 = x[row]
  CLOAD(WF + FE1);
  wstage_rows_bf(myband, xb, lrowr, lane);
  CWRITE();
  __syncthreads();

  // pass 0: E1c0; prefetch FM1c0
  CLOAD(WF + FM1);
  wmfma_lds(myband, chunk, lane, lm, lq, accE);
  __syncthreads();
  CWRITE();
  __syncthreads();

  // pass 1: M1c0 (same band); prefetch E1c1; restage band = x[col]
  CLOAD(WF + FE1 + 16384);
  wmfma_lds(myband, chunk, lane, lm, lq, accM);
  wstage_rows_bf(myband, xb, lcolr, lane);
  __syncthreads();
  CWRITE();
  __syncthreads();

  // pass 2: E1c1; prefetch E1c2; restage band = old edge_attr
  CLOAD(WF + FE1 + 32768);
  wmfma_lds(myband, chunk, lane, lm, lq, accE);
  if (efirst) wstage_seq_f32(myband, (const float*)esrcv, ew0, lane);
  else        wstage_seq_bf (myband, (const bf16_t*)esrcv, ew0, lane);
  __syncthreads();
  CWRITE();
  __syncthreads();

  // pass 3: E1c2; prefetch E2; epi1 hidden_e = relu(accE + Rp[g]) -> band
  CLOAD(WF + FE2);
  wmfma_lds(myband, chunk, lane, lm, lq, accE);
#pragma unroll
  for (int rt = 0; rt < 2; ++rt)
#pragma unroll
    for (int reg = 0; reg < 4; ++reg) {
      int row = rt * 16 + lq * 4 + reg;
      int g = __shfl(lgr, row);
      const float4* rp = (const float4*)(Rp + (size_t)g * 128 + lm * 8);
      float4 ra = rp[0], rb = rp[1];
      float rv[8] = {ra.x, ra.y, ra.z, ra.w, rb.x, rb.y, rb.z, rb.w};
#pragma unroll
      for (int ct = 0; ct < 8; ++ct) {
        int col = ct * 16 + lm;
        myband[row * TP + col] = (bf16_t)fmaxf(accE[rt][ct][reg] + rv[ct], 0.f);
      }
    }
  acc_zero32(accE);
  __syncthreads();
  CWRITE();
  __syncthreads();

  // pass 4: E2; prefetch M1c1; epi2 new_edge -> band + EB (vectorized) + logits
  CLOAD(WF + FM1 + 16384);
  wmfma_lds(myband, chunk, lane, lm, lq, accE);
  {
    float ww8[8], be8[8];
#pragma unroll
    for (int ct = 0; ct < 8; ++ct) { ww8[ct] = Wwv[ct * 16 + lm]; be8[ct] = be2[ct * 16 + lm]; }
#pragma unroll
    for (int rt = 0; rt < 2; ++rt)
#pragma unroll
      for (int reg = 0; reg < 4; ++reg) {
        int row = rt * 16 + lq * 4 + reg;
        int g = __shfl(lgr, row);
        float lsum = 0.f;
#pragma unroll
        for (int ct = 0; ct < 8; ++ct) {
          int col = ct * 16 + lm;
          float v = accE[rt][ct][reg] + be8[ct];
          myband[row * TP + col] = (bf16_t)v;
          lsum += v * ww8[ct];
        }
        if (!last) {
          lsum += __shfl_xor(lsum, 1);
          lsum += __shfl_xor(lsum, 2);
          lsum += __shfl_xor(lsum, 4);
          lsum += __shfl_xor(lsum, 8);
          if (lm == 0) {
            float v2 = lsum + UW[g];
            wl_next[ew0 + row] = v2;
            slwt[w * 32 + row] = v2;
          }
        }
      }
    // vectorized EB store from band (8 x uint4 per lane-pair)
    int r = lane >> 1, h = lane & 1;
    bf16_t* dp = edst + (size_t)(ew0 + r) * DIM + h * 64;
    const bf16_t* sp2 = myband + r * TP + h * 64;
#pragma unroll
    for (int i = 0; i < 8; ++i)
      *(uint4*)(dp + i * 8) = *(const uint4*)(sp2 + i * 8);
  }
  __syncthreads();
  CWRITE();
  __syncthreads();

  // pass 5: M1c1; epi: h_m = relu(accM + bm1) * nw -> band -> MSG  (M2 folded into node)
  wmfma_lds(myband, chunk, lane, lm, lq, accM);
  {
    float bm18[8];
#pragma unroll
    for (int ct = 0; ct < 8; ++ct) bm18[ct] = bm1[ct * 16 + lm];
#pragma unroll
    for (int rt = 0; rt < 2; ++rt)
#pragma unroll
      for (int reg = 0; reg < 4; ++reg) {
        int row = rt * 16 + lq * 4 + reg;
        float nwv = __shfl(lnwr, row);
#pragma unroll
        for (int ct = 0; ct < 8; ++ct) {
          int col = ct * 16 + lm;
          myband[row * TP + col] = (bf16_t)(fmaxf(accM[rt][ct][reg] + bm18[ct], 0.f) * nwv);
        }
      }
    int r = lane >> 1, h = lane & 1;
    bf16_t* dp = msg + (size_t)(ew0 + r) * DIM + h * 64;
    const bf16_t* sp2 = myband + r * TP + h * 64;
#pragma unroll
    for (int i = 0; i < 8; ++i)
      *(uint4*)(dp + i * 8) = *(const uint4*)(sp2 + i * 8);
  }

  // per-wave softmax partials for next layer (coalesced [g][wave] layout)
  if (!last) {
    int g = lane >> 1, seg = lane & 1;
    float m = -1e30f, s = 0.f;
    for (int i = seg * 16; i < seg * 16 + 16; ++i) {
      int gi = __shfl(lgr, i);
      if (gi == g) {
        float v = slwt[w * 32 + i];
        if (v > m) { s = s * expf(m - v) + 1.f; m = v; }
        else s += expf(v - m);
      }
    }
    merge_shfl(m, s, 2);
    if (seg == 0) { pm[g * FWAVES + blk * 4 + w] = m; ps[g * FWAVES + blk * 4 + w] = s; }
  }
#undef CLOAD
#undef CWRITE
}

// ---------------- CSR gather: Hsum[n]/cnt (bf16) + rnw[n] = (sum nw)/cnt ----------------
__global__ __launch_bounds__(256) void gn_gather(
    const bf16_t* __restrict__ msg, const float* __restrict__ nw,
    const int* __restrict__ off, const int* __restrict__ eidx,
    bf16_t* recvb, float* rnw) {
  int w = threadIdx.x >> 6, lane = threadIdx.x & 63;
  int n = blockIdx.x * 4 + w;
  int o0 = off[n], o1 = off[n + 1];
  float a0 = 0.f, a1 = 0.f, snw = 0.f;
  int i = o0;
  int e = (i < o1) ? eidx[i] : 0;
  for (; i < o1; ++i) {
    int en = (i + 1 < o1) ? eidx[i + 1] : 0;
    bf16x2 v = *(const bf16x2*)(msg + (size_t)e * DIM + lane * 2);
    a0 += (float)v[0];
    a1 += (float)v[1];
    snw += nw[e];
    e = en;
  }
  float ic = 1.f / fmaxf((float)(o1 - o0), 1.f);
  bf16x2 o; o[0] = (bf16_t)(a0 * ic); o[1] = (bf16_t)(a1 * ic);
  *(bf16x2*)(recvb + (size_t)n * DIM + lane * 2) = o;
  if (lane == 0) rnw[n] = snw * ic;
}

// ---------------- node update POST kernel (recv@Wcomb + rnw*bm2u + PRE -> relu -> @Wu2) ----------------
__global__ __launch_bounds__(64, 3) void gn_node(
    bf16_t* xdst, const bf16_t* recvb, const float* rnw, const float* pre,
    const bf16_t* __restrict__ WF, const float* bu2, const float* bm2u) {
  __shared__ bf16_t sA[32 * TP];

  int lane = threadIdx.x;
  int nb = blockIdx.x;
  int n0 = nb * 32;
  int lm = lane & 15, lq = lane >> 4;

  float rnwreg = 0.f;
  if (lane < 32) rnwreg = rnw[n0 + lane];

  wstage_seq_bf(sA, recvb, n0, lane);

  f32x4 acc[2][8];
  acc_zero32(acc);
  wmfma_gk128(sA, WF + FWC, lane, lm, lq, acc);              // (Hsum/cnt) @ Wcomb

  // hidden_u = relu(acc + rnw*bm2u + PRE)
  const float* pp = pre + (size_t)nb * 4096 + lane;
  float bm2u8[8];
#pragma unroll
  for (int ct = 0; ct < 8; ++ct) bm2u8[ct] = bm2u[ct * 16 + lm];
#pragma unroll
  for (int rt = 0; rt < 2; ++rt)
#pragma unroll
    for (int reg = 0; reg < 4; ++reg) {
      int row = rt * 16 + lq * 4 + reg;
      float rv = __shfl(rnwreg, row);
#pragma unroll
      for (int ct = 0; ct < 8; ++ct) {
        int col = ct * 16 + lm;
        sA[row * TP + col] = (bf16_t)fmaxf(
            acc[rt][ct][reg] + rv * bm2u8[ct] + pp[((rt * 32 + reg * 8 + ct) << 6)], 0.f);
      }
    }
  acc_zero32(acc);
  wmfma_gk128(sA, WF + FU2, lane, lm, lq, acc);

  {
    float bu28[8];
#pragma unroll
    for (int ct = 0; ct < 8; ++ct) bu28[ct] = bu2[ct * 16 + lm];
#pragma unroll
    for (int rt = 0; rt < 2; ++rt)
#pragma unroll
      for (int reg = 0; reg < 4; ++reg) {
        int row = rt * 16 + lq * 4 + reg;
        bf16_t* dr = xdst + (size_t)(n0 + row) * DIM;
#pragma unroll
        for (int ct = 0; ct < 8; ++ct) {
          int col = ct * 16 + lm;
          dr[col] = (bf16_t)(acc[rt][ct][reg] + bu28[ct]);
        }
      }
  }
}

// ---------------- evidence -> K/V projection ----------------
__global__ __launch_bounds__(64, 3) void gn_ev(
    const bf16_t* xsrc, const bf16_t* __restrict__ WF,
    const float* bk, const float* bv, float* kb, float* vb) {
  __shared__ bf16_t sA[32 * TP];

  int lane = threadIdx.x;
  int n0 = blockIdx.x * 32;
  int sel = blockIdx.y;
  const bf16_t* Wf = WF + (sel ? FV : FK);
  const float* bias = sel ? bv : bk;
  float* dst = sel ? vb : kb;
  int lm = lane & 15, lq = lane >> 4;

  {
    int r = lane >> 1, h = lane & 1;
    const bf16_t* sp = xsrc + (size_t)(n0 + r) * DIM + h * 64;
    bf16_t* dp = sA + r * TP + h * 64;
#pragma unroll
    for (int i = 0; i < 8; ++i) {
      uint4 v = *(const uint4*)(sp + i * 8);
      bf16_t tmp[8];
      *(uint4*)tmp = v;
      bf16x8 tv;
#pragma unroll
      for (int j = 0; j < 8; ++j) {
        float f = (float)tmp[j];
        tv[j] = (bf16_t)(0.5f * f * (1.f + erff(f * 0.70710678118654752f)));
      }
      *(bf16x8*)(dp + i * 8) = tv;
    }
  }

  f32x4 acc[2][8];
  acc_zero32(acc);
  wmfma_gk128(sA, Wf, lane, lm, lq, acc);

  {
    float b8[8];
#pragma unroll
    for (int ct = 0; ct < 8; ++ct) b8[ct] = bias[ct * 16 + lm];
#pragma unroll
    for (int rt = 0; rt < 2; ++rt)
#pragma unroll
      for (int reg = 0; reg < 4; ++reg) {
        int row = rt * 16 + lq * 4 + reg;
        float* dr = dst + (size_t)(n0 + row) * DIM;
#pragma unroll
        for (int ct = 0; ct < 8; ++ct) {
          int col = ct * 16 + lm;
          dr[col] = acc[rt][ct][reg] + b8[ct];
        }
      }
  }
}

// ---------------- pooled edge: wave-private LDS accumulators, NO atomics ----------------
__global__ __launch_bounds__(256, 2) void gn_pooled_edge(
    const bf16_t* __restrict__ eb, const float* __restrict__ nw,
    const int* __restrict__ gb, float* pep) {
  __shared__ float loc[4][4096];
  int t = threadIdx.x;
  int lane = t & 63, w = t >> 6;
  float* myloc = loc[w];
  for (int i = lane; i < 4096; i += 64) myloc[i] = 0.f;
  // no barrier: each wave touches only its own buffer until the final merge

  int wid = blockIdx.x * 4 + w;
  int c0 = lane * 2;
  for (int e = wid; e < NEDGE; e += PBLK * 4) {
    int g = gb[e];
    float nwt = nw[e];
    bf16x2 v = *(const bf16x2*)(eb + (size_t)e * DIM + c0);
    float* a = myloc + g * 128 + c0;
    float2 cur = *(float2*)a;
    cur.x += (float)v[0] * nwt;
    cur.y += (float)v[1] * nwt;
    *(float2*)a = cur;
  }
  __syncthreads();
  float* pp = pep + (size_t)blockIdx.x * 4096;
  for (int i = t; i < 4096; i += 256)
    pp[i] = loc[0][i] + loc[1][i] + loc[2][i] + loc[3][i];
}

// ---------------- attention pool ----------------
__global__ void gn_att(const float* qb, const float* kb, const float* vb, const int* non, float* out) {
  int b = blockIdx.x >> 1, h = blockIdx.x & 1, t = threadIdx.x;
  __shared__ float qv[64];
  __shared__ float sc[625];
  __shared__ float red[256];
  if (t < 64) qv[t] = qb[b * 128 + h * 64 + t];
  __syncthreads();
  int nn = non[b];
  const float4* qv4 = (const float4*)qv;
  for (int l = t; l < 625; l += 256) {
    float acc = 0.f;
    const float4* kr = (const float4*)(kb + ((size_t)(b * 625 + l)) * DIM + h * 64);
#pragma unroll
    for (int d2 = 0; d2 < 16; ++d2) {
      float4 kv = kr[d2];
      float4 qq = qv4[d2];
      acc += qq.x * kv.x + qq.y * kv.y + qq.z * kv.z + qq.w * kv.w;
    }
    sc[l] = (l < nn) ? acc * 0.125f : -1e30f;
  }
  __syncthreads();
  float m = -1e30f;
  for (int l = t; l < 625; l += 256) m = fmaxf(m, sc[l]);
  red[t] = m; __syncthreads();
  for (int s2 = 128; s2 > 0; s2 >>= 1) { if (t < s2) red[t] = fmaxf(red[t], red[t + s2]); __syncthreads(); }
  m = red[0]; __syncthreads();
  float ssum = 0.f;
  for (int l = t; l < 625; l += 256) { float e = expf(sc[l] - m); sc[l] = e; ssum += e; }
  red[t] = ssum; __syncthreads();
  for (int s2 = 128; s2 > 0; s2 >>= 1) { if (t < s2) red[t] += red[t + s2]; __syncthreads(); }
  float inv = 1.f / red[0];
  __syncthreads();
  int d = t & 63, seg = t >> 6;
  float acc = 0.f;
  for (int l = seg; l < 625; l += 4) acc += sc[l] * vb[((size_t)(b * 625 + l)) * DIM + h * 64 + d];
  red[t] = acc; __syncthreads();
  if (t < 64) {
    float v = red[t] + red[64 + t] + red[128 + t] + red[192 + t];
    out[b * 256 + 128 + h * 64 + d] = v * inv;
  }
}

// sum the PBLK per-block pooled-edge partials straight into out
__global__ void gn_fin(const float* pep, float* out) {
  int i = blockIdx.x * 256 + threadIdx.x;
  float s = 0.f;
#pragma unroll 8
  for (int blk = 0; blk < PBLK; ++blk) s += pep[(size_t)blk * 4096 + i];
  int b = i >> 7, c = i & 127;
  out[b * 256 + c] = s;
}

// ---------------- launcher ----------------
extern "C" void kernel_launch(void* const* d_in, const int* in_sizes, int n_in,
                              void* d_out, int out_size, void* d_ws, size_t ws_size,
                              hipStream_t stream) {
  const float* x   = (const float*)d_in[0];
  const float* ea  = (const float*)d_in[1];
  const float* u   = (const float*)d_in[2];
  const float* qa  = (const float*)d_in[3];
  const float* We1 = (const float*)d_in[4];
  const float* be1 = (const float*)d_in[5];
  const float* We2 = (const float*)d_in[6];
  const float* be2 = (const float*)d_in[7];
  const float* Ww  = (const float*)d_in[8];
  const float* bw  = (const float*)d_in[9];
  const float* Wm1 = (const float*)d_in[10];
  const float* bm1 = (const float*)d_in[11];
  const float* Wm2 = (const float*)d_in[12];
  const float* bm2 = (const float*)d_in[13];
  const float* Wu1 = (const float*)d_in[14];
  const float* bu1 = (const float*)d_in[15];
  const float* Wu2 = (const float*)d_in[16];
  const float* bu2 = (const float*)d_in[17];
  const float* Wq  = (const float*)d_in[18];
  const float* bq  = (const float*)d_in[19];
  const float* Wk  = (const float*)d_in[20];
  const float* bk  = (const float*)d_in[21];
  const float* Wv  = (const float*)d_in[22];
  const float* bv  = (const float*)d_in[23];
  const int* ei   = (const int*)d_in[24];
  const int* nbat = (const int*)d_in[25];
  const int* non  = (const int*)d_in[26];
  float* out = (float*)d_out;

  char* p = (char*)d_ws;
  auto alloc = [&](size_t bytes) { char* r = p; p += (bytes + 255) & ~(size_t)255; return r; };
  bf16_t* EB    = (bf16_t*)alloc((size_t)NEDGE * DIM * 2);
  bf16_t* XB    = (bf16_t*)alloc((size_t)N_NODES * DIM * 2);
  bf16_t* XB0   = (bf16_t*)alloc((size_t)N_NODES * DIM * 2);
  bf16_t* MSG   = (bf16_t*)alloc((size_t)NEDGE * DIM * 2);
  bf16_t* RECVB = (bf16_t*)alloc((size_t)N_NODES * DIM * 2);
  int*   CNTI = (int*)alloc((size_t)N_NODES * 4);
  int*   OFF  = (int*)alloc((size_t)(N_NODES + 1) * 4);
  int*   CURS = (int*)alloc((size_t)N_NODES * 4);
  int*   EIDX = (int*)alloc((size_t)NEDGE * 4);
  float* WL   = (float*)alloc((size_t)NEDGE * 4);
  float* WLn  = (float*)alloc((size_t)NEDGE * 4);
  float* NW   = (float*)alloc((size_t)NEDGE * 4);
  float* RNW  = (float*)alloc((size_t)N_NODES * 4);
  int*   GB   = (int*)alloc((size_t)NEDGE * 4);
  float* PM   = (float*)alloc((size_t)32 * FWAVES * 4);
  float* PS   = (float*)alloc((size_t)32 * FWAVES * 4);
  float* MG   = (float*)alloc(32 * 4);
  float* SG   = (float*)alloc(32 * 4);
  float* RP   = (float*)alloc(32 * 128 * 4);
  float* UW   = (float*)alloc(32 * 4);
  float* WCOMB= (float*)alloc(16384 * 4);
  float* BM2U = (float*)alloc(128 * 4);
  bf16_t* WF  = (bf16_t*)alloc((size_t)WF_ELEMS * 2);
  float* QB   = (float*)alloc(32 * 128 * 4);
  float* KB   = (float*)alloc((size_t)N_NODES * DIM * 4);
  float* VB   = (float*)alloc((size_t)N_NODES * DIM * 4);
  float* PEP  = (float*)alloc((size_t)PBLK * 4096 * 4);
  float* PRE  = (float*)alloc((size_t)N_NODES * DIM * 4);

  hipMemsetAsync(CNTI, 0, (size_t)N_NODES * 4, stream);

  gn_xcvt<<<(N_NODES * DIM / 4 + 255) / 256, 256, 0, stream>>>(x, XB0);
  gn_wcomb<<<64, 256, 0, stream>>>(Wm2, Wu1, WCOMB);
  gn_fragw<<<(WF_ELEMS + 255) / 256, 256, 0, stream>>>(We1, We2, Wm1, Wm2, Wu1, Wu2, Wk, Wv, WCOMB, WF);
  gn_uprep<<<16, 256, 0, stream>>>(u, We1, be1, Ww, bw, bm2, Wu1, RP, UW, BM2U);
  gn_counti<<<1250, 256, 0, stream>>>(ei, CNTI);
  gn_scan<<<1, 256, 0, stream>>>(CNTI, OFF, CURS);
  gn_eidx<<<1250, 256, 0, stream>>>(ei, CURS, EIDX);
  gn_q<<<32, 256, 0, stream>>>(qa, Wq, bq, QB);
  gn_wl0<<<2500, 256, 0, stream>>>(ea, Ww, UW, ei, nbat, WL, GB);
  gn_part0<<<EBLK, 256, 0, stream>>>(WL, GB, PM, PS);

  for (int layer = 0; layer < 3; ++layer) {
    int first = (layer == 0) ? 1 : 0;
    int last = (layer == 2) ? 1 : 0;
    const bf16_t* xs = first ? XB0 : XB;
    const void* es = first ? (const void*)ea : (const void*)EB;
    float* cur = (layer == 1) ? WLn : WL;
    float* nxt = (layer == 1) ? WL : WLn;
    gn_reduce_ms<<<32, 256, 0, stream>>>(PM, PS, MG, SG, first ? EBLK : FWAVES);
    gn_fused<<<EBLK + GPRE, 256, 0, stream>>>(xs, es, first, EB, WF, RP, UW, Ww,
                                              be2, bm1, cur, MG, SG,
                                              nxt, PM, PS, last, ei, GB, MSG,
                                              u, bu1, nbat, PRE, NW);
    gn_gather<<<5000, 256, 0, stream>>>(MSG, NW, OFF, EIDX, RECVB, RNW);
    gn_node<<<NBLK, 64, 0, stream>>>(XB, RECVB, RNW, PRE, WF, bu2, BM2U);
  }

  gn_pooled_edge<<<PBLK, 256, 0, stream>>>(EB, NW, GB, PEP);
  gn_ev<<<dim3(NBLK, 2), 64, 0, stream>>>(XB, WF, bk, bv, KB, VB);
  gn_att<<<64, 256, 0, stream>>>(QB, KB, VB, non, out);
  gn_fin<<<16, 256, 0, stream>>>(PEP, out);
}

// Round 9
// 1258.899 us; speedup vs baseline: 1.1782x; 1.0482x over previous
//
#include <hip/hip_runtime.h>
#include <math.h>

typedef __bf16 bf16_t;
typedef bf16_t bf16x8 __attribute__((ext_vector_type(8)));
typedef bf16_t bf16x4 __attribute__((ext_vector_type(4)));
typedef bf16_t bf16x2 __attribute__((ext_vector_type(2)));
typedef float  f32x4  __attribute__((ext_vector_type(4)));

#define N_NODES 20000
#define NEDGE   320000
#define DIM     128
#define TP      136           // LDS band row stride (elems)
#define EBLK    2500          // NEDGE / 128 (fused edge blocks, 4 waves x 32 edges)
#define FWAVES  10000         // NEDGE / 32  (per-wave partial count)
#define NBLK    625           // N_NODES / 32
#define GPRE    157           // ceil(20000 / 128) PRE tail blocks
#define PBLK    512           // pooled-edge blocks (4 waves each, wave-private LDS acc)

// ---- WF (MFMA b-frag-layout weights, bf16); each 128x128 chunk = 16384 elems = 32KB ----
// seg: 0-2 We1(kc0..2) | 3 WCE=We2@We1[256:384] | 4 Wm1(kc0) | 5 WCM=We2@Wm1[128:256]
//      6 Wm2(unused) | 7-9 Wu1(kc0..2) | 10 Wu2 | 11 Wk | 12 Wv | 13 WC1=Wm2@Wu1[128:256]
#define FE1  0
#define FCE  49152
#define FM1  65536
#define FCM  81920
#define FU1  114688
#define FU2  163840
#define FK   180224
#define FV   196608
#define FWC  212992
#define WF_ELEMS 229376       // 14 * 16384

// ---------------- shared helpers ----------------
__device__ __forceinline__ void acc_zero32(f32x4 acc[2][8]) {
  f32x4 z = {0.f, 0.f, 0.f, 0.f};
#pragma unroll
  for (int i = 0; i < 2; ++i)
#pragma unroll
    for (int j = 0; j < 8; ++j) acc[i][j] = z;
}

// ---- 32-row band staging (2 lanes per row, 8x16B per lane) ----
__device__ __forceinline__ void wstage_rows_bf(bf16_t* sA, const bf16_t* src, int rowreg, int lane) {
  int r = lane >> 1, h = lane & 1;
  int row = __shfl(rowreg, r);
  const bf16_t* sp = src + (size_t)row * DIM + h * 64;
  bf16_t* dp = sA + r * TP + h * 64;
#pragma unroll
  for (int i = 0; i < 8; ++i)
    *(uint4*)(dp + i * 8) = *(const uint4*)(sp + i * 8);
}

__device__ __forceinline__ void wstage_rows_f32(bf16_t* sA, const float* src, int rowreg, int lane) {
  int r = lane >> 1, h = lane & 1;
  int row = __shfl(rowreg, r);
  const float* sp = src + (size_t)row * DIM + h * 64;
  bf16_t* dp = sA + r * TP + h * 64;
#pragma unroll
  for (int i = 0; i < 8; ++i) {
    float4 f0 = *(const float4*)(sp + i * 8);
    float4 f1 = *(const float4*)(sp + i * 8 + 4);
    bf16x8 tv;
    tv[0]=(bf16_t)f0.x; tv[1]=(bf16_t)f0.y; tv[2]=(bf16_t)f0.z; tv[3]=(bf16_t)f0.w;
    tv[4]=(bf16_t)f1.x; tv[5]=(bf16_t)f1.y; tv[6]=(bf16_t)f1.z; tv[7]=(bf16_t)f1.w;
    *(bf16x8*)(dp + i * 8) = tv;
  }
}

__device__ __forceinline__ void wstage_seq_bf(bf16_t* sA, const bf16_t* src, int base, int lane) {
  int r = lane >> 1, h = lane & 1;
  const bf16_t* sp = src + (size_t)(base + r) * DIM + h * 64;
  bf16_t* dp = sA + r * TP + h * 64;
#pragma unroll
  for (int i = 0; i < 8; ++i)
    *(uint4*)(dp + i * 8) = *(const uint4*)(sp + i * 8);
}

__device__ __forceinline__ void wstage_seq_f32(bf16_t* sA, const float* src, int base, int lane) {
  int r = lane >> 1, h = lane & 1;
  const float* sp = src + (size_t)(base + r) * DIM + h * 64;
  bf16_t* dp = sA + r * TP + h * 64;
#pragma unroll
  for (int i = 0; i < 8; ++i) {
    float4 f0 = *(const float4*)(sp + i * 8);
    float4 f1 = *(const float4*)(sp + i * 8 + 4);
    bf16x8 tv;
    tv[0]=(bf16_t)f0.x; tv[1]=(bf16_t)f0.y; tv[2]=(bf16_t)f0.z; tv[3]=(bf16_t)f0.w;
    tv[4]=(bf16_t)f1.x; tv[5]=(bf16_t)f1.y; tv[6]=(bf16_t)f1.z; tv[7]=(bf16_t)f1.w;
    *(bf16x8*)(dp + i * 8) = tv;
  }
}

// stage a full 32KB weight chunk into LDS cooperatively (256 threads x 128B) - PRE path only
__device__ __forceinline__ void chunk_stage(bf16_t* ch, const bf16_t* __restrict__ src, int t) {
#pragma unroll
  for (int i = 0; i < 8; ++i) {
    int idx = (i * 256 + t) * 8;
    *(uint4*)(ch + idx) = *(const uint4*)(src + idx);
  }
}

// one K=128 MFMA pass: A from private band, B-frags from LDS chunk
__device__ __forceinline__ void wmfma_lds(const bf16_t* sA, const bf16_t* ch,
                                          int lane, int lm, int lq, f32x4 acc[2][8]) {
#pragma unroll
  for (int kk = 0; kk < 4; ++kk) {
    int ko = kk * 32 + lq * 8;
    bf16x8 a0 = *(const bf16x8*)(sA + lm * TP + ko);
    bf16x8 a1 = *(const bf16x8*)(sA + (16 + lm) * TP + ko);
    const bf16_t* wp = ch + (kk << 12) + (lane << 3);
#pragma unroll
    for (int ct = 0; ct < 8; ++ct) {
      bf16x8 bfr = *(const bf16x8*)(wp + (ct << 9));
      acc[0][ct] = __builtin_amdgcn_mfma_f32_16x16x32_bf16(a0, bfr, acc[0][ct], 0, 0, 0);
      acc[1][ct] = __builtin_amdgcn_mfma_f32_16x16x32_bf16(a1, bfr, acc[1][ct], 0, 0, 0);
    }
  }
}

// one K=128 MFMA pass with B-frags streamed from global WF (small kernels)
__device__ __forceinline__ void wmfma_gk128(const bf16_t* sA, const bf16_t* __restrict__ Wf,
                                            int lane, int lm, int lq, f32x4 acc[2][8]) {
#pragma unroll
  for (int kk = 0; kk < 4; ++kk) {
    int ko = kk * 32 + lq * 8;
    bf16x8 a0 = *(const bf16x8*)(sA + lm * TP + ko);
    bf16x8 a1 = *(const bf16x8*)(sA + (16 + lm) * TP + ko);
    const bf16_t* wp = Wf + ((kk * 8) << 9) + (lane << 3);
#pragma unroll
    for (int ct = 0; ct < 8; ++ct) {
      bf16x8 bfr = *(const bf16x8*)(wp + (ct << 9));
      acc[0][ct] = __builtin_amdgcn_mfma_f32_16x16x32_bf16(a0, bfr, acc[0][ct], 0, 0, 0);
      acc[1][ct] = __builtin_amdgcn_mfma_f32_16x16x32_bf16(a1, bfr, acc[1][ct], 0, 0, 0);
    }
  }
}

// online-softmax merge over 2^k lanes, state (m,s)
__device__ __forceinline__ void merge_shfl(float& m, float& s, int width) {
  for (int k = 1; k < width; k <<= 1) {
    float m2 = __shfl_xor(m, k), s2 = __shfl_xor(s, k);
    float M = fmaxf(m, m2), ns = 0.f;
    if (m  > -1e29f) ns += s  * expf(m  - M);
    if (m2 > -1e29f) ns += s2 * expf(m2 - M);
    m = M; s = ns;
  }
}

// ---------------- prep kernels ----------------
__global__ void gn_xcvt(const float* x, bf16_t* xb) {
  int i = blockIdx.x * 256 + threadIdx.x;
  if (i < N_NODES * DIM / 4) {
    float4 f = ((const float4*)x)[i];
    bf16x4 o; o[0]=(bf16_t)f.x; o[1]=(bf16_t)f.y; o[2]=(bf16_t)f.z; o[3]=(bf16_t)f.w;
    *(bf16x4*)(xb + (size_t)i * 4) = o;
  }
}

// composed weights: WC1 = Wm2@Wu1[128:256]; WCE = We2@We1[256:384]; WCM = We2@Wm1[128:256]
__global__ void gn_wcomb(const float* Wm2, const float* Wu1, const float* We2,
                         const float* We1, const float* Wm1,
                         float* wc1, float* wce, float* wcm) {
  int idx = blockIdx.x * 256 + threadIdx.x;
  if (idx >= 16384) return;
  int i = idx >> 7, j = idx & 127;
  float acc = 0.f;
  if (blockIdx.y == 0) {
    for (int m = 0; m < 128; ++m) acc += Wm2[i * 128 + m] * Wu1[(128 + m) * 128 + j];
    wc1[idx] = acc;
  } else if (blockIdx.y == 1) {
    for (int m = 0; m < 128; ++m) acc += We2[i * 128 + m] * We1[(256 + m) * 128 + j];
    wce[idx] = acc;
  } else {
    for (int m = 0; m < 128; ++m) acc += We2[i * 128 + m] * Wm1[(128 + m) * 128 + j];
    wcm[idx] = acc;
  }
}

__global__ void gn_fragw(const float* We1, const float* Wce, const float* Wm1, const float* Wcm,
                         const float* Wm2, const float* Wu1, const float* Wu2,
                         const float* Wk, const float* Wv, const float* Wc1, bf16_t* WF) {
  int idx = blockIdx.x * 256 + threadIdx.x;
  if (idx >= WF_ELEMS) return;
  int seg = idx >> 14;
  const float* W; int kc;
  switch (seg) {
    case 0:  W = We1; kc = 0; break;
    case 1:  W = We1; kc = 1; break;
    case 2:  W = We1; kc = 2; break;
    case 3:  W = Wce; kc = 0; break;
    case 4:  W = Wm1; kc = 0; break;
    case 5:  W = Wcm; kc = 0; break;
    case 6:  W = Wm2; kc = 0; break;
    case 7:  W = Wu1; kc = 0; break;
    case 8:  W = Wu1; kc = 1; break;
    case 9:  W = Wu1; kc = 2; break;
    case 10: W = Wu2; kc = 0; break;
    case 11: W = Wk;  kc = 0; break;
    case 12: W = Wv;  kc = 0; break;
    default: W = Wc1; kc = 0; break;
  }
  int r = idx & 16383;
  int j = r & 7, lane = (r >> 3) & 63, ct = (r >> 9) & 7, kk = (r >> 12) & 3;
  int k = kc * 128 + kk * 32 + (lane >> 4) * 8 + j;
  int n = ct * 16 + (lane & 15);
  WF[idx] = (bf16_t)W[k * 128 + n];
}

// Rp0/Rp12 (epilogue-transposed), uw/uw2, bm2u, bm1p, wv
__global__ void gn_uprep(const float* u, const float* We1, const float* be1,
                         const float* Ww, const float* bw,
                         const float* bm2, const float* Wu1,
                         const float* bm1, const float* be2,
                         const float* Wm1, const float* We2,
                         float* Rp0, float* Rp12, float* uw, float* uw2,
                         float* bm2u, float* bm1p, float* wv) {
  int t = threadIdx.x;
  for (int idx = blockIdx.x * 256 + t; idx < 32 * 128; idx += gridDim.x * 256) {
    int g = idx >> 7, c = idx & 127;
    float acc = be1[c];
    for (int k = 0; k < 128; ++k) acc += u[g * 128 + k] * We1[(384 + k) * 128 + c];
    float be12 = 0.f;
    for (int k = 0; k < 128; ++k) be12 += be2[k] * We1[(256 + k) * 128 + c];
    int tc = g * 128 + (c & 15) * 8 + (c >> 4);
    Rp0[tc] = acc;
    Rp12[tc] = acc + be12;
  }
  if (blockIdx.x == 0 && t < 32) {
    float acc = bw[0];
    for (int k = 0; k < 128; ++k) acc += u[t * 128 + k] * Ww[128 + k];
    float bsh = 0.f;
    for (int c = 0; c < 128; ++c) bsh += be2[c] * Ww[c];
    uw[t] = acc;
    uw2[t] = acc + bsh;
  }
  if (blockIdx.x == 1 && t < 128) {
    float a1 = 0.f, a2 = 0.f, a3 = 0.f;
    for (int k = 0; k < 128; ++k) {
      a1 += bm2[k] * Wu1[(128 + k) * 128 + t];
      a2 += be2[k] * Wm1[(128 + k) * 128 + t];
      a3 += We2[t * 128 + k] * Ww[k];
    }
    bm2u[t] = a1;
    bm1p[t] = bm1[t] + a2;
    wv[t] = a3;
  }
}

// int in-degree count
__global__ void gn_counti(const int* ei, int* cnti) {
  int e = blockIdx.x * 256 + threadIdx.x;
  if (e < NEDGE) atomicAdd(&cnti[ei[NEDGE + e]], 1);
}

// single-block exclusive scan of cnti -> off (and cursor copy)
__global__ void gn_scan(const int* cnti, int* off, int* curs) {
  __shared__ int part[256];
  int t = threadIdx.x;
  int base = t * 80;
  int lim = base + 80; if (lim > N_NODES) lim = N_NODES;
  int s = 0;
  for (int i = base; i < lim; ++i) s += cnti[i];
  part[t] = s;
  __syncthreads();
  for (int d = 1; d < 256; d <<= 1) {
    int add = (t >= d) ? part[t - d] : 0;
    __syncthreads();
    part[t] += add;
    __syncthreads();
  }
  int pfx = (t == 0) ? 0 : part[t - 1];
  for (int i = base; i < lim; ++i) {
    off[i] = pfx; curs[i] = pfx; pfx += cnti[i];
  }
  if (t == 0) off[N_NODES] = NEDGE;
}

// scatter edge ids into CSR order by destination
__global__ void gn_eidx(const int* ei, int* curs, int* eidx) {
  int e = blockIdx.x * 256 + threadIdx.x;
  if (e < NEDGE) {
    int c = ei[NEDGE + e];
    int pos = atomicAdd(&curs[c], 1);
    eidx[pos] = e;
  }
}

__global__ void gn_q(const float* qa, const float* Wq, const float* bq, float* qb) {
  int b = blockIdx.x, t = threadIdx.x;
  int c = t & 127, half = t >> 7;
  const float* qrow = qa + b * 1024 + half * 512;
  float acc = 0.f;
  for (int k = 0; k < 512; ++k) acc += qrow[k] * Wq[(half * 512 + k) * 128 + c];
  __shared__ float red[256];
  red[t] = acc;
  __syncthreads();
  if (half == 0) qb[b * 128 + c] = red[c] + red[128 + c] + bq[c];
}

__global__ void gn_wl0(const float* ea, const float* Ww, const float* uw,
                       const int* ei, const int* nbat, float* wl, int* gb) {
  int t = threadIdx.x;
  int sub = t & 15, grp = t >> 4;
  for (int e = blockIdx.x * 16 + grp; e < NEDGE; e += gridDim.x * 16) {
    const float* er = ea + (size_t)e * DIM + sub * 8;
    float s = 0.f;
#pragma unroll
    for (int j = 0; j < 8; ++j) s += er[j] * Ww[sub * 8 + j];
#pragma unroll
    for (int m = 1; m < 16; m <<= 1) s += __shfl_xor(s, m);
    if (sub == 0) {
      int g = nbat[ei[e]];
      wl[e] = s + uw[g];
      gb[e] = g;
    }
  }
}

// per-128-edge-block softmax partials, layer 0.  pm layout: [g][wave] coalesced.
__global__ void gn_part0(const float* wl, const int* gb, float* pm, float* ps) {
  __shared__ float lv[128];
  __shared__ int   lgg[128];
  int t = threadIdx.x, blk = blockIdx.x, e0 = blk * 128;
  if (t < 128) { lv[t] = wl[e0 + t]; lgg[t] = gb[e0 + t]; }
  __syncthreads();
  int g = t >> 3, seg = t & 7;
  float m = -1e30f, s = 0.f;
  for (int i = seg * 16; i < seg * 16 + 16; ++i)
    if (lgg[i] == g) {
      float v = lv[i];
      if (v > m) { s = s * expf(m - v) + 1.f; m = v; }
      else s += expf(v - m);
    }
  merge_shfl(m, s, 8);
  if (seg == 0) { pm[g * FWAVES + blk] = m; ps[g * FWAVES + blk] = s; }
}

__global__ void gn_reduce_ms(const float* pm, const float* ps, float* mg, float* sg, int nb) {
  int g = blockIdx.x, t = threadIdx.x;
  __shared__ float red[256];
  float m = -1e30f;
  for (int i = t; i < nb; i += 256) m = fmaxf(m, pm[g * FWAVES + i]);
  red[t] = m; __syncthreads();
  for (int s2 = 128; s2 > 0; s2 >>= 1) { if (t < s2) red[t] = fmaxf(red[t], red[t + s2]); __syncthreads(); }
  m = red[0]; __syncthreads();
  float s = 0.f;
  for (int i = t; i < nb; i += 256) {
    float sb = ps[g * FWAVES + i];
    if (sb > 0.f) s += sb * expf(pm[g * FWAVES + i] - m);
  }
  red[t] = s; __syncthreads();
  for (int s2 = 128; s2 > 0; s2 >>= 1) { if (t < s2) red[t] += red[t + s2]; __syncthreads(); }
  if (t == 0) { mg[g] = m; sg[g] = red[0]; }
}

// ---------------- fused edge+message kernel (5 passes; E2 AND M2 folded out) ----------------
// edge state = HE = relu(E1) (bf16 in EB).  new_edge never materializes:
//   next-layer E1c2 uses WCE=We2@We1_e;  M1c1 uses WCM=We2@Wm1_e;  logits use wv=We2@Ww_e;
//   pooled-edge pools HE and applies We2 afterwards (gn_fin2).
__global__ __launch_bounds__(256, 2) void gn_fused(
    const bf16_t* __restrict__ xb,
    const void* esrcv, int efirst,      // layer0: f32 ea; else bf16 HE (EB)
    bf16_t* edst,                       // HE out
    const bf16_t* __restrict__ WF,
    const float* Rp, const float* UW2, const float* wv, const float* bm1p,
    const float* wl_cur, const float* mg, const float* sg,
    float* wl_next, float* pm, float* ps, int last,
    const int* ei, const int* gb, bf16_t* msg,
    const float* uu, const float* bu1, const int* nbat, float* pre,
    float* nwout) {
  __shared__ bf16_t chunk[16384];
  __shared__ bf16_t band[4][32 * TP];
  __shared__ float slwt[128];

  int t = threadIdx.x;
  int w = t >> 6, lane = t & 63;
  int lm = lane & 15, lq = lane >> 4;
  int blk = blockIdx.x;
  bf16_t* myband = band[w];

  if (blk >= EBLK) {
    // ---- PRE node partial: 128 nodes per block, 32 per wave ----
    int nb128 = blk - EBLK;
    int gb32 = nb128 * 4 + w;
    int lrow = 0, lgr = 0;
    if (lane < 32) {
      int node = gb32 * 32 + lane;
      if (node > N_NODES - 1) node = N_NODES - 1;
      lrow = node;
      lgr = nbat[node];
    }
    f32x4 acc[2][8];
    acc_zero32(acc);
    wstage_rows_bf(myband, xb, lrow, lane);
    chunk_stage(chunk, WF + FU1, t);
    __syncthreads();
    wmfma_lds(myband, chunk, lane, lm, lq, acc);             // x part
    __syncthreads();
    wstage_rows_f32(myband, uu, lgr, lane);
    chunk_stage(chunk, WF + FU1 + 32768, t);
    __syncthreads();
    wmfma_lds(myband, chunk, lane, lm, lq, acc);             // u part
    if (gb32 < NBLK) {
      float* pp = pre + (size_t)gb32 * 4096 + lane;
#pragma unroll
      for (int rt = 0; rt < 2; ++rt)
#pragma unroll
        for (int reg = 0; reg < 4; ++reg)
#pragma unroll
          for (int ct = 0; ct < 8; ++ct)
            pp[((rt * 32 + reg * 8 + ct) << 6)] = acc[rt][ct][reg] + bu1[ct * 16 + lm];
    }
    return;
  }

  int e0 = blk * 128;
  int ew0 = e0 + w * 32;               // this wave's first edge
  int lrowr = 0, lcolr = 0, lgr = 0;
  float lnwr = 0.f;
  if (lane < 32) {
    int e = ew0 + lane;
    lrowr = ei[e];
    lcolr = ei[NEDGE + e];
    lgr = gb[e];
    lnwr = expf(wl_cur[e] - mg[lgr]) / sg[lgr];
    nwout[e] = lnwr;
  }

  f32x4 accE[2][8], accM[2][8];
  acc_zero32(accE);
  acc_zero32(accM);

  uint4 c0, c1, c2, c3, c4, c5, c6, c7;
#define CLOAD(SRC) { const uint4* _s = (const uint4*)(SRC) + t; \
  c0 = _s[0];    c1 = _s[256];  c2 = _s[512];  c3 = _s[768]; \
  c4 = _s[1024]; c5 = _s[1280]; c6 = _s[1536]; c7 = _s[1792]; }
#define CWRITE() { uint4* _d = (uint4*)chunk + t; \
  _d[0] = c0;    _d[256] = c1;  _d[512] = c2;  _d[768] = c3; \
  _d[1024] = c4; _d[1280] = c5; _d[1536] = c6; _d[1792] = c7; }

  // prologue: chunk C0 = E1c0; band = x[row]
  CLOAD(WF + FE1);
  wstage_rows_bf(myband, xb, lrowr, lane);
  CWRITE();
  __syncthreads();

  // p0: E1c0 -> accE; prefetch M1c0
  CLOAD(WF + FM1);
  wmfma_lds(myband, chunk, lane, lm, lq, accE);
  __syncthreads();
  CWRITE();
  __syncthreads();

  // p1: M1c0 (same band) -> accM; prefetch E1c1; restage band = x[col]
  CLOAD(WF + FE1 + 16384);
  wmfma_lds(myband, chunk, lane, lm, lq, accM);
  wstage_rows_bf(myband, xb, lcolr, lane);
  __syncthreads();
  CWRITE();
  __syncthreads();

  // p2: E1c1 -> accE; prefetch E1c2-variant; restage band = e-input (ea | HE_prev)
  CLOAD(efirst ? (WF + FE1 + 32768) : (WF + FCE));
  wmfma_lds(myband, chunk, lane, lm, lq, accE);
  if (efirst) wstage_seq_f32(myband, (const float*)esrcv, ew0, lane);
  else        wstage_seq_bf (myband, (const bf16_t*)esrcv, ew0, lane);
  __syncthreads();
  CWRITE();
  __syncthreads();

  // p3: E1c2 -> accE; prefetch M1c1 (WCM); epi1: HE = relu(accE+Rp) -> band + EB + logits
  CLOAD(WF + FCM);
  wmfma_lds(myband, chunk, lane, lm, lq, accE);
  {
    float ww8[8];
#pragma unroll
    for (int ct = 0; ct < 8; ++ct) ww8[ct] = wv[ct * 16 + lm];
#pragma unroll
    for (int rt = 0; rt < 2; ++rt)
#pragma unroll
      for (int reg = 0; reg < 4; ++reg) {
        int row = rt * 16 + lq * 4 + reg;
        int g = __shfl(lgr, row);
        const float4* rp = (const float4*)(Rp + (size_t)g * 128 + lm * 8);
        float4 ra = rp[0], rb = rp[1];
        float rv[8] = {ra.x, ra.y, ra.z, ra.w, rb.x, rb.y, rb.z, rb.w};
        float lsum = 0.f;
#pragma unroll
        for (int ct = 0; ct < 8; ++ct) {
          int col = ct * 16 + lm;
          float v = fmaxf(accE[rt][ct][reg] + rv[ct], 0.f);
          myband[row * TP + col] = (bf16_t)v;
          lsum += v * ww8[ct];
        }
        if (!last) {
          lsum += __shfl_xor(lsum, 1);
          lsum += __shfl_xor(lsum, 2);
          lsum += __shfl_xor(lsum, 4);
          lsum += __shfl_xor(lsum, 8);
          if (lm == 0) {
            float v2 = lsum + UW2[g];
            wl_next[ew0 + row] = v2;
            slwt[w * 32 + row] = v2;
          }
        }
      }
    // vectorized HE store from band
    int r = lane >> 1, h = lane & 1;
    bf16_t* dp = edst + (size_t)(ew0 + r) * DIM + h * 64;
    const bf16_t* sp2 = myband + r * TP + h * 64;
#pragma unroll
    for (int i = 0; i < 8; ++i)
      *(uint4*)(dp + i * 8) = *(const uint4*)(sp2 + i * 8);
  }
  __syncthreads();
  CWRITE();
  __syncthreads();

  // p4: M1c1 (HE band @ WCM) -> accM; epi: MSG = relu(accM + bm1p) * nw
  wmfma_lds(myband, chunk, lane, lm, lq, accM);
  {
    float bm18[8];
#pragma unroll
    for (int ct = 0; ct < 8; ++ct) bm18[ct] = bm1p[ct * 16 + lm];
#pragma unroll
    for (int rt = 0; rt < 2; ++rt)
#pragma unroll
      for (int reg = 0; reg < 4; ++reg) {
        int row = rt * 16 + lq * 4 + reg;
        float nwv = __shfl(lnwr, row);
#pragma unroll
        for (int ct = 0; ct < 8; ++ct) {
          int col = ct * 16 + lm;
          myband[row * TP + col] = (bf16_t)(fmaxf(accM[rt][ct][reg] + bm18[ct], 0.f) * nwv);
        }
      }
    int r = lane >> 1, h = lane & 1;
    bf16_t* dp = msg + (size_t)(ew0 + r) * DIM + h * 64;
    const bf16_t* sp2 = myband + r * TP + h * 64;
#pragma unroll
    for (int i = 0; i < 8; ++i)
      *(uint4*)(dp + i * 8) = *(const uint4*)(sp2 + i * 8);
  }

  // per-wave softmax partials for next layer (coalesced [g][wave] layout)
  if (!last) {
    int g = lane >> 1, seg = lane & 1;
    float m = -1e30f, s = 0.f;
    for (int i = seg * 16; i < seg * 16 + 16; ++i) {
      int gi = __shfl(lgr, i);
      if (gi == g) {
        float v = slwt[w * 32 + i];
        if (v > m) { s = s * expf(m - v) + 1.f; m = v; }
        else s += expf(v - m);
      }
    }
    merge_shfl(m, s, 2);
    if (seg == 0) { pm[g * FWAVES + blk * 4 + w] = m; ps[g * FWAVES + blk * 4 + w] = s; }
  }
#undef CLOAD
#undef CWRITE
}

// ---------------- CSR gather (4-way unrolled): Hsum/cnt (bf16) + rnw ----------------
__global__ __launch_bounds__(256) void gn_gather(
    const bf16_t* __restrict__ msg, const float* __restrict__ nw,
    const int* __restrict__ off, const int* __restrict__ eidx,
    bf16_t* recvb, float* rnw) {
  int w = threadIdx.x >> 6, lane = threadIdx.x & 63;
  int n = blockIdx.x * 4 + w;
  int o0 = off[n], o1 = off[n + 1];
  float a0 = 0.f, a1 = 0.f, snw = 0.f;
  int i = o0;
  for (; i + 3 < o1; i += 4) {
    int e0 = eidx[i], e1 = eidx[i + 1], e2 = eidx[i + 2], e3 = eidx[i + 3];
    bf16x2 v0 = *(const bf16x2*)(msg + (size_t)e0 * DIM + lane * 2);
    bf16x2 v1 = *(const bf16x2*)(msg + (size_t)e1 * DIM + lane * 2);
    bf16x2 v2 = *(const bf16x2*)(msg + (size_t)e2 * DIM + lane * 2);
    bf16x2 v3 = *(const bf16x2*)(msg + (size_t)e3 * DIM + lane * 2);
    a0 += (float)v0[0] + (float)v1[0] + (float)v2[0] + (float)v3[0];
    a1 += (float)v0[1] + (float)v1[1] + (float)v2[1] + (float)v3[1];
    snw += nw[e0] + nw[e1] + nw[e2] + nw[e3];
  }
  for (; i < o1; ++i) {
    int e = eidx[i];
    bf16x2 v = *(const bf16x2*)(msg + (size_t)e * DIM + lane * 2);
    a0 += (float)v[0];
    a1 += (float)v[1];
    snw += nw[e];
  }
  float ic = 1.f / fmaxf((float)(o1 - o0), 1.f);
  bf16x2 o; o[0] = (bf16_t)(a0 * ic); o[1] = (bf16_t)(a1 * ic);
  *(bf16x2*)(recvb + (size_t)n * DIM + lane * 2) = o;
  if (lane == 0) rnw[n] = snw * ic;
}

// ---------------- node update POST kernel (recv@WC1 + rnw*bm2u + PRE -> relu -> @Wu2) ----------------
__global__ __launch_bounds__(64, 3) void gn_node(
    bf16_t* xdst, const bf16_t* recvb, const float* rnw, const float* pre,
    const bf16_t* __restrict__ WF, const float* bu2, const float* bm2u) {
  __shared__ bf16_t sA[32 * TP];

  int lane = threadIdx.x;
  int nb = blockIdx.x;
  int n0 = nb * 32;
  int lm = lane & 15, lq = lane >> 4;

  float rnwreg = 0.f;
  if (lane < 32) rnwreg = rnw[n0 + lane];

  wstage_seq_bf(sA, recvb, n0, lane);

  f32x4 acc[2][8];
  acc_zero32(acc);
  wmfma_gk128(sA, WF + FWC, lane, lm, lq, acc);              // (Hsum/cnt) @ WC1

  const float* pp = pre + (size_t)nb * 4096 + lane;
  float bm2u8[8];
#pragma unroll
  for (int ct = 0; ct < 8; ++ct) bm2u8[ct] = bm2u[ct * 16 + lm];
#pragma unroll
  for (int rt = 0; rt < 2; ++rt)
#pragma unroll
    for (int reg = 0; reg < 4; ++reg) {
      int row = rt * 16 + lq * 4 + reg;
      float rv = __shfl(rnwreg, row);
#pragma unroll
      for (int ct = 0; ct < 8; ++ct) {
        int col = ct * 16 + lm;
        sA[row * TP + col] = (bf16_t)fmaxf(
            acc[rt][ct][reg] + rv * bm2u8[ct] + pp[((rt * 32 + reg * 8 + ct) << 6)], 0.f);
      }
    }
  acc_zero32(acc);
  wmfma_gk128(sA, WF + FU2, lane, lm, lq, acc);

  {
    float bu28[8];
#pragma unroll
    for (int ct = 0; ct < 8; ++ct) bu28[ct] = bu2[ct * 16 + lm];
#pragma unroll
    for (int rt = 0; rt < 2; ++rt)
#pragma unroll
      for (int reg = 0; reg < 4; ++reg) {
        int row = rt * 16 + lq * 4 + reg;
        bf16_t* dr = xdst + (size_t)(n0 + row) * DIM;
#pragma unroll
        for (int ct = 0; ct < 8; ++ct) {
          int col = ct * 16 + lm;
          dr[col] = (bf16_t)(acc[rt][ct][reg] + bu28[ct]);
        }
      }
  }
}

// ---------------- evidence -> K/V projection ----------------
__global__ __launch_bounds__(64, 3) void gn_ev(
    const bf16_t* xsrc, const bf16_t* __restrict__ WF,
    const float* bk, const float* bv, float* kb, float* vb) {
  __shared__ bf16_t sA[32 * TP];

  int lane = threadIdx.x;
  int n0 = blockIdx.x * 32;
  int sel = blockIdx.y;
  const bf16_t* Wf = WF + (sel ? FV : FK);
  const float* bias = sel ? bv : bk;
  float* dst = sel ? vb : kb;
  int lm = lane & 15, lq = lane >> 4;

  {
    int r = lane >> 1, h = lane & 1;
    const bf16_t* sp = xsrc + (size_t)(n0 + r) * DIM + h * 64;
    bf16_t* dp = sA + r * TP + h * 64;
#pragma unroll
    for (int i = 0; i < 8; ++i) {
      uint4 v = *(const uint4*)(sp + i * 8);
      bf16_t tmp[8];
      *(uint4*)tmp = v;
      bf16x8 tv;
#pragma unroll
      for (int j = 0; j < 8; ++j) {
        float f = (float)tmp[j];
        tv[j] = (bf16_t)(0.5f * f * (1.f + erff(f * 0.70710678118654752f)));
      }
      *(bf16x8*)(dp + i * 8) = tv;
    }
  }

  f32x4 acc[2][8];
  acc_zero32(acc);
  wmfma_gk128(sA, Wf, lane, lm, lq, acc);

  {
    float b8[8];
#pragma unroll
    for (int ct = 0; ct < 8; ++ct) b8[ct] = bias[ct * 16 + lm];
#pragma unroll
    for (int rt = 0; rt < 2; ++rt)
#pragma unroll
      for (int reg = 0; reg < 4; ++reg) {
        int row = rt * 16 + lq * 4 + reg;
        float* dr = dst + (size_t)(n0 + row) * DIM;
#pragma unroll
        for (int ct = 0; ct < 8; ++ct) {
          int col = ct * 16 + lm;
          dr[col] = acc[rt][ct][reg] + b8[ct];
        }
      }
  }
}

// ---------------- pooled edge over HE: wave-private LDS accumulators + per-graph nw sums ----------------
__global__ __launch_bounds__(256, 2) void gn_pooled_edge(
    const bf16_t* __restrict__ he, const float* __restrict__ nw,
    const int* __restrict__ gb, float* pep, float* pepn) {
  __shared__ float loc[4][4096];
  __shared__ float nws[4][32];
  int t = threadIdx.x;
  int lane = t & 63, w = t >> 6;
  float* myloc = loc[w];
  for (int i = lane; i < 4096; i += 64) myloc[i] = 0.f;
  if (lane < 32) nws[w][lane] = 0.f;

  int wid = blockIdx.x * 4 + w;
  int c0 = lane * 2;
  for (int e = wid; e < NEDGE; e += PBLK * 4) {
    int g = gb[e];
    float nwt = nw[e];
    bf16x2 v = *(const bf16x2*)(he + (size_t)e * DIM + c0);
    float* a = myloc + g * 128 + c0;
    float2 cur = *(float2*)a;
    cur.x += (float)v[0] * nwt;
    cur.y += (float)v[1] * nwt;
    *(float2*)a = cur;
    if (lane == 0) nws[w][g] += nwt;
  }
  __syncthreads();
  float* pp = pep + (size_t)blockIdx.x * 4096;
  for (int i = t; i < 4096; i += 256)
    pp[i] = loc[0][i] + loc[1][i] + loc[2][i] + loc[3][i];
  if (t < 32)
    pepn[blockIdx.x * 32 + t] = nws[0][t] + nws[1][t] + nws[2][t] + nws[3][t];
}

// ---------------- attention pool (1024 threads: 4x memory parallelism) ----------------
__global__ __launch_bounds__(1024) void gn_att(
    const float* qb, const float* kb, const float* vb, const int* non, float* out) {
  int b = blockIdx.x >> 1, h = blockIdx.x & 1, t = threadIdx.x;
  __shared__ float qv[64];
  __shared__ float sc[625];
  __shared__ float red[1024];
  if (t < 64) qv[t] = qb[b * 128 + h * 64 + t];
  __syncthreads();
  int nn = non[b];
  const float4* qv4 = (const float4*)qv;
  for (int l = t; l < 625; l += 1024) {
    float acc = 0.f;
    const float4* kr = (const float4*)(kb + ((size_t)(b * 625 + l)) * DIM + h * 64);
#pragma unroll
    for (int d2 = 0; d2 < 16; ++d2) {
      float4 kv = kr[d2];
      float4 qq = qv4[d2];
      acc += qq.x * kv.x + qq.y * kv.y + qq.z * kv.z + qq.w * kv.w;
    }
    sc[l] = (l < nn) ? acc * 0.125f : -1e30f;
  }
  __syncthreads();
  float m = -1e30f;
  for (int l = t; l < 625; l += 1024) m = fmaxf(m, sc[l]);
  red[t] = m; __syncthreads();
  for (int s2 = 512; s2 > 0; s2 >>= 1) { if (t < s2) red[t] = fmaxf(red[t], red[t + s2]); __syncthreads(); }
  m = red[0]; __syncthreads();
  float ssum = 0.f;
  for (int l = t; l < 625; l += 1024) { float e = expf(sc[l] - m); sc[l] = e; ssum += e; }
  red[t] = ssum; __syncthreads();
  for (int s2 = 512; s2 > 0; s2 >>= 1) { if (t < s2) red[t] += red[t + s2]; __syncthreads(); }
  float inv = 1.f / red[0];
  __syncthreads();
  int d = t & 63, seg = t >> 6;                  // 16 segments
  float acc = 0.f;
  for (int l = seg; l < 625; l += 16) acc += sc[l] * vb[((size_t)(b * 625 + l)) * DIM + h * 64 + d];
  red[t] = acc; __syncthreads();
  if (t < 64) {
    float v = 0.f;
#pragma unroll
    for (int s = 0; s < 16; ++s) v += red[s * 64 + t];
    out[b * 256 + 128 + h * 64 + d] = v * inv;
  }
}

// reduce pooled partials -> SPOOL[32][128] and NWG[32]
__global__ void gn_fin1(const float* pep, const float* pepn, float* spool, float* nwg) {
  int i = blockIdx.x * 256 + threadIdx.x;        // 16 x 256 = 4096
  float s = 0.f;
#pragma unroll 8
  for (int blk = 0; blk < PBLK; ++blk) s += pep[(size_t)blk * 4096 + i];
  spool[i] = s;
  if (i < 32) {
    float sn = 0.f;
    for (int blk = 0; blk < PBLK; ++blk) sn += pepn[blk * 32 + i];
    nwg[i] = sn;
  }
}

// pooled_edge = SPOOL @ We2 + NWG * be2  -> out[:, 0:128]
__global__ void gn_fin2(const float* spool, const float* nwg, const float* We2,
                        const float* be2, float* out) {
  int i = blockIdx.x * 256 + threadIdx.x;        // 16 x 256 = 4096
  int b = i >> 7, c = i & 127;
  float acc = nwg[b] * be2[c];
  for (int k = 0; k < 128; ++k) acc += spool[b * 128 + k] * We2[k * 128 + c];
  out[b * 256 + c] = acc;
}

// ---------------- launcher ----------------
extern "C" void kernel_launch(void* const* d_in, const int* in_sizes, int n_in,
                              void* d_out, int out_size, void* d_ws, size_t ws_size,
                              hipStream_t stream) {
  const float* x   = (const float*)d_in[0];
  const float* ea  = (const float*)d_in[1];
  const float* u   = (const float*)d_in[2];
  const float* qa  = (const float*)d_in[3];
  const float* We1 = (const float*)d_in[4];
  const float* be1 = (const float*)d_in[5];
  const float* We2 = (const float*)d_in[6];
  const float* be2 = (const float*)d_in[7];
  const float* Ww  = (const float*)d_in[8];
  const float* bw  = (const float*)d_in[9];
  const float* Wm1 = (const float*)d_in[10];
  const float* bm1 = (const float*)d_in[11];
  const float* Wm2 = (const float*)d_in[12];
  const float* bm2 = (const float*)d_in[13];
  const float* Wu1 = (const float*)d_in[14];
  const float* bu1 = (const float*)d_in[15];
  const float* Wu2 = (const float*)d_in[16];
  const float* bu2 = (const float*)d_in[17];
  const float* Wq  = (const float*)d_in[18];
  const float* bq  = (const float*)d_in[19];
  const float* Wk  = (const float*)d_in[20];
  const float* bk  = (const float*)d_in[21];
  const float* Wv  = (const float*)d_in[22];
  const float* bv  = (const float*)d_in[23];
  const int* ei   = (const int*)d_in[24];
  const int* nbat = (const int*)d_in[25];
  const int* non  = (const int*)d_in[26];
  float* out = (float*)d_out;

  char* p = (char*)d_ws;
  auto alloc = [&](size_t bytes) { char* r = p; p += (bytes + 255) & ~(size_t)255; return r; };
  bf16_t* EB    = (bf16_t*)alloc((size_t)NEDGE * DIM * 2);     // HE state
  bf16_t* XB    = (bf16_t*)alloc((size_t)N_NODES * DIM * 2);
  bf16_t* XB0   = (bf16_t*)alloc((size_t)N_NODES * DIM * 2);
  bf16_t* MSG   = (bf16_t*)alloc((size_t)NEDGE * DIM * 2);
  bf16_t* RECVB = (bf16_t*)alloc((size_t)N_NODES * DIM * 2);
  int*   CNTI = (int*)alloc((size_t)N_NODES * 4);
  int*   OFF  = (int*)alloc((size_t)(N_NODES + 1) * 4);
  int*   CURS = (int*)alloc((size_t)N_NODES * 4);
  int*   EIDX = (int*)alloc((size_t)NEDGE * 4);
  float* WL   = (float*)alloc((size_t)NEDGE * 4);
  float* WLn  = (float*)alloc((size_t)NEDGE * 4);
  float* NW   = (float*)alloc((size_t)NEDGE * 4);
  float* RNW  = (float*)alloc((size_t)N_NODES * 4);
  int*   GB   = (int*)alloc((size_t)NEDGE * 4);
  float* PM   = (float*)alloc((size_t)32 * FWAVES * 4);
  float* PS   = (float*)alloc((size_t)32 * FWAVES * 4);
  float* MG   = (float*)alloc(32 * 4);
  float* SG   = (float*)alloc(32 * 4);
  float* RP0  = (float*)alloc(32 * 128 * 4);
  float* RP12 = (float*)alloc(32 * 128 * 4);
  float* UW   = (float*)alloc(32 * 4);
  float* UW2  = (float*)alloc(32 * 4);
  float* WC1  = (float*)alloc(16384 * 4);
  float* WCE  = (float*)alloc(16384 * 4);
  float* WCM  = (float*)alloc(16384 * 4);
  float* BM2U = (float*)alloc(128 * 4);
  float* BM1P = (float*)alloc(128 * 4);
  float* WVV  = (float*)alloc(128 * 4);
  bf16_t* WF  = (bf16_t*)alloc((size_t)WF_ELEMS * 2);
  float* QB   = (float*)alloc(32 * 128 * 4);
  float* KB   = (float*)alloc((size_t)N_NODES * DIM * 4);
  float* VB   = (float*)alloc((size_t)N_NODES * DIM * 4);
  float* PEP  = (float*)alloc((size_t)PBLK * 4096 * 4);
  float* PEPN = (float*)alloc((size_t)PBLK * 32 * 4);
  float* SPOOL= (float*)alloc(4096 * 4);
  float* NWG  = (float*)alloc(32 * 4);
  float* PRE  = (float*)alloc((size_t)N_NODES * DIM * 4);

  hipMemsetAsync(CNTI, 0, (size_t)N_NODES * 4, stream);

  gn_xcvt<<<(N_NODES * DIM / 4 + 255) / 256, 256, 0, stream>>>(x, XB0);
  gn_wcomb<<<dim3(64, 3), 256, 0, stream>>>(Wm2, Wu1, We2, We1, Wm1, WC1, WCE, WCM);
  gn_fragw<<<(WF_ELEMS + 255) / 256, 256, 0, stream>>>(We1, WCE, Wm1, WCM, Wm2, Wu1, Wu2, Wk, Wv, WC1, WF);
  gn_uprep<<<16, 256, 0, stream>>>(u, We1, be1, Ww, bw, bm2, Wu1, bm1, be2, Wm1, We2,
                                   RP0, RP12, UW, UW2, BM2U, BM1P, WVV);
  gn_counti<<<1250, 256, 0, stream>>>(ei, CNTI);
  gn_scan<<<1, 256, 0, stream>>>(CNTI, OFF, CURS);
  gn_eidx<<<1250, 256, 0, stream>>>(ei, CURS, EIDX);
  gn_q<<<32, 256, 0, stream>>>(qa, Wq, bq, QB);
  gn_wl0<<<2500, 256, 0, stream>>>(ea, Ww, UW, ei, nbat, WL, GB);
  gn_part0<<<EBLK, 256, 0, stream>>>(WL, GB, PM, PS);

  for (int layer = 0; layer < 3; ++layer) {
    int first = (layer == 0) ? 1 : 0;
    int last = (layer == 2) ? 1 : 0;
    const bf16_t* xs = first ? XB0 : XB;
    const void* es = first ? (const void*)ea : (const void*)EB;
    const float* rp = first ? RP0 : RP12;
    float* cur = (layer == 1) ? WLn : WL;
    float* nxt = (layer == 1) ? WL : WLn;
    gn_reduce_ms<<<32, 256, 0, stream>>>(PM, PS, MG, SG, first ? EBLK : FWAVES);
    gn_fused<<<EBLK + GPRE, 256, 0, stream>>>(xs, es, first, EB, WF, rp, UW2, WVV, BM1P,
                                              cur, MG, SG, nxt, PM, PS, last, ei, GB, MSG,
                                              u, bu1, nbat, PRE, NW);
    gn_gather<<<5000, 256, 0, stream>>>(MSG, NW, OFF, EIDX, RECVB, RNW);
    gn_node<<<NBLK, 64, 0, stream>>>(XB, RECVB, RNW, PRE, WF, bu2, BM2U);
  }

  gn_pooled_edge<<<PBLK, 256, 0, stream>>>(EB, NW, GB, PEP, PEPN);
  gn_ev<<<dim3(NBLK, 2), 64, 0, stream>>>(XB, WF, bk, bv, KB, VB);
  gn_att<<<64, 1024, 0, stream>>>(QB, KB, VB, non, out);
  gn_fin1<<<16, 256, 0, stream>>>(PEP, PEPN, SPOOL, NWG);
  gn_fin2<<<16, 256, 0, stream>>>(SPOOL, NWG, We2, be2, out);
}